// Round 1
// baseline (1596.949 us; speedup 1.0000x reference)
//
#include <hip/hip_runtime.h>
#include <math.h>

#define Bq    128
#define Dq    128
#define Hq    50
#define NEGq  4
#define Lq    30
#define Sq    55      // H + 1 + NEG
#define NPGq  80
#define Nq    10240   // B * NPG
#define Eq    163840  // N * 16
#define NEWSq 7040    // B * S
#define BEq   28160   // NEWS * 4
#define WVOCq 50000
#define NEG1q 5

__device__ __forceinline__ float leaky_f(float x) { return x > 0.f ? x : 0.2f * x; }

// ---------------------------------------------------------------- CSR build
__global__ void k_count(const int* __restrict__ dst, int* __restrict__ cnt, int ne) {
    int e = blockIdx.x * blockDim.x + threadIdx.x;
    if (e < ne) atomicAdd(&cnt[dst[e]], 1);
}

__global__ __launch_bounds__(1024) void k_scan(const int* __restrict__ cnt, int* __restrict__ off, int n) {
    __shared__ int part[1024];
    int tid = threadIdx.x;
    int chunk = (n + 1023) >> 10;
    int s0 = tid * chunk;
    int s1 = s0 + chunk; if (s1 > n) s1 = n;
    int s = 0;
    for (int i = s0; i < s1; ++i) s += cnt[i];
    part[tid] = s;
    __syncthreads();
    for (int d = 1; d < 1024; d <<= 1) {
        int v = (tid >= d) ? part[tid - d] : 0;
        __syncthreads();
        part[tid] += v;
        __syncthreads();
    }
    int base = (tid > 0) ? part[tid - 1] : 0;
    for (int i = s0; i < s1; ++i) { off[i] = base; base += cnt[i]; }
    if (tid == 0) off[n] = part[1023];
}

__global__ void k_scatter(const int* __restrict__ src, const int* __restrict__ dst,
                          int* __restrict__ cur, int* __restrict__ out_src, int ne) {
    int e = blockIdx.x * blockDim.x + threadIdx.x;
    if (e < ne) {
        int slot = atomicAdd(&cur[dst[e]], 1);
        out_src[slot] = src[e];
    }
}

// ---------------------------------------------------------------- gathers
__global__ void k_embed(const int* __restrict__ nodes, const float* __restrict__ ent,
                        float* __restrict__ out, int n) {
    int i = blockIdx.x * blockDim.x + threadIdx.x;
    if (i < n * 128) {
        int r = i >> 7, d = i & 127;
        out[i] = ent[(long)nodes[r] * 128 + d];
    }
}

// ---------------------------------------------------------------- word scores
#define WPB 16
__global__ __launch_bounds__(128) void k_word_score(
        const float* __restrict__ emb, const float* __restrict__ W,
        const float* __restrict__ bias, const float* __restrict__ vv,
        float* __restrict__ out, int nwords) {
    __shared__ float sW[64 * 128];   // one K-half of W
    __shared__ float sA[WPB][64];
    __shared__ double red[128];
    int tid = threadIdx.x;
    int w0 = blockIdx.x * WPB;
    double acc[WPB];
#pragma unroll
    for (int t = 0; t < WPB; ++t) acc[t] = 0.0;
    for (int kh = 0; kh < 2; ++kh) {
        __syncthreads();
        const float4* W4 = (const float4*)(W + kh * 64 * 128);
        float4* sW4 = (float4*)sW;
        for (int i = tid; i < 64 * 32; i += 128) sW4[i] = W4[i];
        for (int i = tid; i < WPB * 16; i += 128) {
            int wi = i >> 4, c4 = i & 15;
            int w = w0 + wi;
            float4 v = (w < nwords) ? ((const float4*)(emb + (long)w * 128 + kh * 64))[c4]
                                    : make_float4(0.f, 0.f, 0.f, 0.f);
            ((float4*)&sA[wi][0])[c4] = v;
        }
        __syncthreads();
        for (int wi = 0; wi < WPB; ++wi) {
            const float* a = sA[wi];
            double s = acc[wi];
#pragma unroll 8
            for (int i = 0; i < 64; ++i) s += (double)a[i] * (double)sW[i * 128 + tid];
            acc[wi] = s;
        }
    }
    float bf = bias[tid];
    double vf = (double)vv[tid];
    for (int wi = 0; wi < WPB; ++wi) {
        float t = (float)acc[wi] + bf;                 // round dot to f32, then + b (f32)
        float th = (float)tanh((double)t);             // f32 tanh result
        red[tid] = (double)th * vf;
        __syncthreads();
        for (int d = 64; d > 0; d >>= 1) { if (tid < d) red[tid] += red[tid + d]; __syncthreads(); }
        int w = w0 + wi;
        if (tid == 0 && w < nwords) out[w] = (float)red[0];
        __syncthreads();
    }
}

// ---------------------------------------------------------------- title pooling
__global__ __launch_bounds__(128) void k_title_pool(
        const int* __restrict__ title_tok, const float* __restrict__ wscore,
        const float* __restrict__ wemb,
        const int* __restrict__ hist_seqs, const int* __restrict__ hist_lens,
        const int* __restrict__ pos_seq, const int* __restrict__ pos_len,
        const int* __restrict__ neg_seqs, const int* __restrict__ neg_lens,
        float* __restrict__ UTraw, float* __restrict__ news1) {
    int t = blockIdx.x;
    int b = t / Sq, s = t % Sq;
    int nid, len; float* dst;
    if (s < Hq)       { nid = hist_seqs[b * Hq + s]; len = hist_lens[b * Hq + s]; dst = UTraw + (long)(b * Hq + s) * 128; }
    else if (s == Hq) { nid = pos_seq[b];            len = pos_len[b];            dst = news1 + (long)t * 128; }
    else { int g = s - Hq - 1; nid = neg_seqs[b * NEGq + g]; len = neg_lens[b * NEGq + g]; dst = news1 + (long)t * 128; }

    __shared__ int tok[Lq];
    __shared__ float wgt[Lq];
    __shared__ double sden;
    int tid = threadIdx.x;
    if (tid < Lq) tok[tid] = title_tok[(long)nid * Lq + tid];
    __syncthreads();
    if (tid == 0) {
        float mx = -1e30f;
        for (int l = 0; l < len; ++l) { float sc = wscore[tok[l]]; wgt[l] = sc; if (sc > mx) mx = sc; }
        double den = 0.0;
        for (int l = 0; l < len; ++l) {
            float e = (float)exp((double)(wgt[l] - mx));
            wgt[l] = e; den += (double)e;
        }
        sden = den;
    }
    __syncthreads();
    double den = sden;
    double acc = 0.0;
    for (int l = 0; l < len; ++l)
        acc += (double)wgt[l] * (double)wemb[(long)tok[l] * 128 + tid];
    dst[tid] = (float)(acc / den);
}

// ---------------------------------------------------------------- generic 128-matmul (f64 acc)
#define MMR 32
__global__ __launch_bounds__(256) void k_matmul128(const float* __restrict__ A,
                                                   const float* __restrict__ W,
                                                   float* __restrict__ C, int M) {
    __shared__ float sW[64 * 128];
    __shared__ float sA[MMR][64];
    int tid = threadIdx.x;
    int half = tid >> 7, j = tid & 127;
    int r0 = blockIdx.x * MMR;
    double acc[MMR / 2];
#pragma unroll
    for (int t = 0; t < MMR / 2; ++t) acc[t] = 0.0;
    for (int kh = 0; kh < 2; ++kh) {
        __syncthreads();
        const float4* W4 = (const float4*)(W + kh * 64 * 128);
        float4* sW4 = (float4*)sW;
        for (int i = tid; i < 64 * 32; i += 256) sW4[i] = W4[i];
        for (int i = tid; i < MMR * 16; i += 256) {
            int r = i >> 4, c4 = i & 15;
            int rr = r0 + r;
            float4 v = (rr < M) ? ((const float4*)(A + (long)rr * 128 + kh * 64))[c4]
                                : make_float4(0.f, 0.f, 0.f, 0.f);
            ((float4*)&sA[r][0])[c4] = v;
        }
        __syncthreads();
        for (int t = 0; t < MMR / 2; ++t) {
            const float* ar = sA[2 * t + half];
            double a = acc[t];
#pragma unroll 8
            for (int i = 0; i < 64; ++i) a += (double)ar[i] * (double)sW[i * 128 + j];
            acc[t] = a;
        }
    }
    for (int t = 0; t < MMR / 2; ++t) {
        int r = r0 + 2 * t + half;
        if (r < M) C[(long)r * 128 + j] = (float)acc[t];
    }
}

// ---------------------------------------------------------------- row · vec (+ optional scalar bias ptr)
__global__ __launch_bounds__(128) void k_dot1(const float* __restrict__ X, const float* __restrict__ a,
                                              float* __restrict__ o, const float* __restrict__ bptr) {
    __shared__ double red[128];
    int n = blockIdx.x, tid = threadIdx.x;
    red[tid] = (double)X[(long)n * 128 + tid] * (double)a[tid];
    __syncthreads();
    for (int d = 64; d > 0; d >>= 1) { if (tid < d) red[tid] += red[tid + d]; __syncthreads(); }
    if (tid == 0) {
        float dotf = (float)red[0];
        if (bptr) dotf += bptr[0];
        o[n] = dotf;
    }
}

// o[n] = sum_j tanh(T[n][j] + sb[j]) * sv[j]
__global__ __launch_bounds__(128) void k_tanh_dot(const float* __restrict__ T, const float* __restrict__ sb,
                                                  const float* __restrict__ sv, float* __restrict__ o) {
    __shared__ double red[128];
    int n = blockIdx.x, tid = threadIdx.x;
    float t = T[(long)n * 128 + tid] + sb[tid];
    float th = (float)tanh((double)t);
    red[tid] = (double)th * (double)sv[tid];
    __syncthreads();
    for (int d = 64; d > 0; d >>= 1) { if (tid < d) red[tid] += red[tid + d]; __syncthreads(); }
    if (tid == 0) o[n] = (float)red[0];
}

// ---------------------------------------------------------------- GAT / cross-GAT aggregation
#define MAXK 256
__global__ __launch_bounds__(128) void k_edge_agg(
        const int* __restrict__ off, const int* __restrict__ srcs,
        const float* __restrict__ es, const float* __restrict__ ed,
        const float* __restrict__ Hsrc, const float* __restrict__ Xdst,
        float* __restrict__ Out, int mode) {
    int n = blockIdx.x, tid = threadIdx.x;
    int s0 = off[n], k = off[n + 1] - s0;
    float* outp = Out + (long)n * 128;
    if (k == 0) {
        outp[tid] = mode ? Xdst[(long)n * 128 + tid] : 0.f;  // elu(0)=0 (+residual)
        return;
    }
    __shared__ int   sSrc[MAXK];
    __shared__ float sE[MAXK];
    __shared__ float sX[MAXK];
    __shared__ float redf[128];
    __shared__ double redd[128];
    float edn = ed[n];
    float mloc = -1e30f;
    for (int j = tid; j < k; j += 128) {
        int sidx = srcs[s0 + j];
        float e = leaky_f(es[sidx] + edn);
        if (j < MAXK) { sSrc[j] = sidx; sE[j] = e; }
        if (e > mloc) mloc = e;
    }
    redf[tid] = mloc; __syncthreads();
    for (int d = 64; d > 0; d >>= 1) { if (tid < d) redf[tid] = fmaxf(redf[tid], redf[tid + d]); __syncthreads(); }
    float m = redf[0];
    double dloc = 0.0;
    for (int j = tid; j < k; j += 128) {
        float e = (j < MAXK) ? sE[j] : leaky_f(es[srcs[s0 + j]] + edn);
        float ex = (float)exp((double)(e - m));
        if (j < MAXK) sX[j] = ex;
        dloc += (double)ex;
    }
    redd[tid] = dloc; __syncthreads();
    for (int d = 64; d > 0; d >>= 1) { if (tid < d) redd[tid] += redd[tid + d]; __syncthreads(); }
    double den = redd[0] + 1e-16;
    double acc = 0.0;
    for (int j = 0; j < k; ++j) {
        float ex; int sidx;
        if (j < MAXK) { ex = sX[j]; sidx = sSrc[j]; }
        else { sidx = srcs[s0 + j]; float e = leaky_f(es[sidx] + edn); ex = (float)exp((double)(e - m)); }
        float alpha = (float)((double)ex / den);
        acc += (double)alpha * (double)Hsrc[(long)sidx * 128 + tid];
    }
    float v = (float)acc;
    float o = (v > 0.f) ? v : (float)expm1((double)v);
    if (mode) o += Xdst[(long)n * 128 + tid];
    outp[tid] = o;
}

// ---------------------------------------------------------------- self-attention (one block per batch)
__global__ __launch_bounds__(256) void k_self_attn(const float* __restrict__ Q, const float* __restrict__ K,
                                                   const float* __restrict__ V, float* __restrict__ Out,
                                                   int ob_stride) {
    __shared__ float sK[Hq * 129];
    __shared__ float sV[Hq * 128];
    __shared__ float sQr[4][128];
    __shared__ float sEx[4][Hq];
    __shared__ double sDen[4];
    const double SQRTD = (double)11.3137085f;  // f32(sqrt(128))
    int b = blockIdx.x;
    int tid = threadIdx.x;
    int wv = tid >> 6, lane = tid & 63;
    const float* Kb = K + (long)b * Hq * 128;
    const float* Vb = V + (long)b * Hq * 128;
    const float* Qb = Q + (long)b * Hq * 128;
    for (int idx = tid; idx < Hq * 128; idx += 256) {
        int r = idx >> 7, i = idx & 127;
        sK[r * 129 + i] = Kb[idx];
        sV[idx] = Vb[idx];
    }
    __syncthreads();
    for (int rbase = 0; rbase < Hq; rbase += 4) {
        int r = rbase + wv;
        bool active = (r < Hq);
        __syncthreads();
        for (int idx = tid; idx < 4 * 128; idx += 256) {
            int rw = idx >> 7, i = idx & 127;
            int rr = rbase + rw;
            sQr[rw][i] = (rr < Hq) ? Qb[(long)rr * 128 + i] : 0.f;
        }
        __syncthreads();
        float sval = -1e30f;
        if (active && lane < Hq) {
            const float* q = sQr[wv];
            const float* kc = &sK[lane * 129];
            double acc = 0.0;
#pragma unroll 8
            for (int i = 0; i < 128; ++i) acc += (double)q[i] * (double)kc[i];
            sval = (float)(acc / SQRTD);
        }
        float mm = sval;
        for (int o = 32; o > 0; o >>= 1) mm = fmaxf(mm, __shfl_xor(mm, o));
        float ex = (active && lane < Hq) ? (float)exp((double)(sval - mm)) : 0.f;
        double dsum = (double)ex;
        for (int o = 32; o > 0; o >>= 1) dsum += __shfl_xor(dsum, o);
        if (active && lane < Hq) sEx[wv][lane] = ex;
        if (active && lane == 0) sDen[wv] = dsum;
        __syncthreads();
        if (active) {
            double den = sDen[wv];
            const float* exr = sEx[wv];
            double a0 = 0.0, a1 = 0.0;
            for (int c = 0; c < Hq; ++c) {
                double w = (double)exr[c];
                a0 += w * (double)sV[c * 128 + lane];
                a1 += w * (double)sV[c * 128 + lane + 64];
            }
            float* op = Out + (long)b * ob_stride + (long)r * 128;
            op[lane] = (float)(a0 / den);
            op[lane + 64] = (float)(a1 / den);
        }
    }
}

// ---------------------------------------------------------------- copies
__global__ void k_extract_user(const float* __restrict__ NC, float* __restrict__ UT) {
    int idx = blockIdx.x * blockDim.x + threadIdx.x;
    if (idx < Bq * Hq * 128) {
        int d = idx & 127, rh = idx >> 7;
        int b = rh / Hq, h = rh % Hq;
        UT[idx] = NC[((long)(b * Sq + h)) * 128 + d];
    }
}
__global__ void k_copy_targets(const float* __restrict__ NC, float* __restrict__ news2) {
    int idx = blockIdx.x * blockDim.x + threadIdx.x;
    if (idx < Bq * NEG1q * 128) {
        int d = idx & 127, rt = idx >> 7;
        int b = rt / NEG1q, s = Hq + rt % NEG1q;
        long o = ((long)(b * Sq + s)) * 128 + d;
        news2[o] = NC[o];
    }
}

// ---------------------------------------------------------------- masked pooling
__global__ __launch_bounds__(128) void k_mask_pool(const float* __restrict__ X, const float* __restrict__ gate,
        const int* __restrict__ hist_mask, const int* __restrict__ pos_mask, const int* __restrict__ neg_masks,
        float* __restrict__ pooled) {
    int blk = blockIdx.x;
    int b = blk / 6, s = blk % 6;
    int tid = threadIdx.x;
    __shared__ float sEx[NPGq];
    __shared__ float redf[128];
    __shared__ double redd[128];
    int base = b * NPGq;
    float logit = -1e30f; int mk = 0;
    if (tid < NPGq) {
        int n = base + tid;
        mk = (s == 0) ? hist_mask[n] : (s == 1) ? pos_mask[n] : neg_masks[n * NEGq + (s - 2)];
        logit = (mk > 0) ? gate[n] : -1000000000.0f;
    }
    redf[tid] = logit; __syncthreads();
    for (int d = 64; d > 0; d >>= 1) { if (tid < d) redf[tid] = fmaxf(redf[tid], redf[tid + d]); __syncthreads(); }
    float mx = redf[0];
    float ex = 0.f;
    if (tid < NPGq && mk > 0) ex = (float)exp((double)(logit - mx));
    if (tid < NPGq) sEx[tid] = ex;
    redd[tid] = (double)ex; __syncthreads();
    for (int d = 64; d > 0; d >>= 1) { if (tid < d) redd[tid] += redd[tid + d]; __syncthreads(); }
    double den = redd[0] + 1e-16;
    double acc = 0.0;
    for (int n = 0; n < NPGq; ++n)
        acc += (double)sEx[n] * (double)X[((long)(base + n)) * 128 + tid];
    pooled[(long)blk * 128 + tid] = (float)(acc / den);
}

// ---------------------------------------------------------------- user final pool (softmax over H)
__global__ __launch_bounds__(128) void k_user_pool(const float* __restrict__ UT3, const float* __restrict__ score,
                                                   float* __restrict__ uvec) {
    int b = blockIdx.x, tid = threadIdx.x;
    __shared__ float sEx[Hq];
    __shared__ float redf[128];
    __shared__ double redd[128];
    float sv = (tid < Hq) ? score[b * Hq + tid] : -1e30f;
    redf[tid] = sv; __syncthreads();
    for (int d = 64; d > 0; d >>= 1) { if (tid < d) redf[tid] = fmaxf(redf[tid], redf[tid + d]); __syncthreads(); }
    float mx = redf[0];
    float ex = (tid < Hq) ? (float)exp((double)(sv - mx)) : 0.f;
    if (tid < Hq) sEx[tid] = ex;
    redd[tid] = (double)ex; __syncthreads();
    for (int d = 64; d > 0; d >>= 1) { if (tid < d) redd[tid] += redd[tid + d]; __syncthreads(); }
    double den = redd[0];
    double acc = 0.0;
    for (int h = 0; h < Hq; ++h)
        acc += (double)sEx[h] * (double)UT3[((long)(b * Hq + h)) * 128 + tid];
    uvec[(long)b * 128 + tid] = (float)(acc / den);
}

// ---------------------------------------------------------------- final gated score
__global__ __launch_bounds__(128) void k_final(const float* __restrict__ pooled, const float* __restrict__ uvec,
        const float* __restrict__ NC2, const float* __restrict__ wwW, const float* __restrict__ wwb,
        float* __restrict__ out) {
    int blk = blockIdx.x;
    int b = blk / NEG1q, g = blk % NEG1q;
    int tid = threadIdx.x;
    __shared__ double redd[128];
    const float* ug = pooled + (long)(b * 6 + 0) * 128;
    const float* tg = pooled + (long)(b * 6 + 1 + g) * 128;
    const float* ut = uvec + (long)b * 128;
    const float* tt = NC2 + (long)(b * Sq + Hq + g) * 128;
    double w0 = (double)wwW[tid], w1 = (double)wwW[128 + tid];

    redd[tid] = (double)ug[tid] * w0 + (double)ut[tid] * w1;
    __syncthreads();
    for (int d = 64; d > 0; d >>= 1) { if (tid < d) redd[tid] += redd[tid + d]; __syncthreads(); }
    float su = (float)redd[0] + wwb[0];
    float uwf = (float)(1.0 / (1.0 + exp(-(double)su)));
    __syncthreads();

    redd[tid] = (double)tg[tid] * w0 + (double)tt[tid] * w1;
    __syncthreads();
    for (int d = 64; d > 0; d >>= 1) { if (tid < d) redd[tid] += redd[tid + d]; __syncthreads(); }
    float st = (float)redd[0] + wwb[0];
    float twf = (float)(1.0 / (1.0 + exp(-(double)st)));
    __syncthreads();

    float uh = uwf * ug[tid] + (1.f - uwf) * ut[tid];
    float th = twf * tg[tid] + (1.f - twf) * tt[tid];
    redd[tid] = (double)uh * (double)th;
    __syncthreads();
    for (int d = 64; d > 0; d >>= 1) { if (tid < d) redd[tid] += redd[tid + d]; __syncthreads(); }
    if (tid == 0) out[blk] = (float)redd[0];
}

// ================================================================ launch
extern "C" void kernel_launch(void* const* d_in, const int* in_sizes, int n_in,
                              void* d_out, int out_size, void* d_ws, size_t ws_size,
                              hipStream_t stream) {
    // ---- inputs
    const int*   nodes      = (const int*)d_in[0];
    const int*   ei_src     = (const int*)d_in[1];
    const int*   ei_dst     = ei_src + Eq;
    const int*   bi_news    = (const int*)d_in[2];   // bi_edge_index[0]: news ids
    const int*   bi_node    = bi_news + BEq;         // bi_edge_index[1]: node ids
    const int*   hist_mask  = (const int*)d_in[4];
    const int*   pos_mask   = (const int*)d_in[5];
    const int*   neg_masks  = (const int*)d_in[6];
    const int*   hist_seqs  = (const int*)d_in[7];
    const int*   hist_lens  = (const int*)d_in[8];
    const int*   pos_seq    = (const int*)d_in[9];
    const int*   pos_len    = (const int*)d_in[10];
    const int*   neg_seqs   = (const int*)d_in[11];
    const int*   neg_lens   = (const int*)d_in[12];
    const int*   title_tok  = (const int*)d_in[13];
    const float* ent_emb    = (const float*)d_in[14];
    const float* word_emb   = (const float*)d_in[15];
    const float* te_W  = (const float*)d_in[16];
    const float* te_b  = (const float*)d_in[17];
    const float* te_v  = (const float*)d_in[18];
    const float* ue1_Wq = (const float*)d_in[19];
    const float* ue1_Wk = (const float*)d_in[20];
    const float* ue1_Wv = (const float*)d_in[21];
    const float* ue2_Wq = (const float*)d_in[22];
    const float* ue2_Wk = (const float*)d_in[23];
    const float* ue2_Wv = (const float*)d_in[24];
    const float* ue3_Wq = (const float*)d_in[25];
    const float* ue3_Wk = (const float*)d_in[26];
    const float* ue3_Wv = (const float*)d_in[27];
    const float* g1_W  = (const float*)d_in[28];
    const float* g1_as = (const float*)d_in[29];
    const float* g1_ad = (const float*)d_in[30];
    const float* g2_W  = (const float*)d_in[31];
    const float* g2_as = (const float*)d_in[32];
    const float* g2_ad = (const float*)d_in[33];
    const float* cg1_Ws = (const float*)d_in[34];
    const float* cg1_Wd = (const float*)d_in[35];
    const float* cg1_as = (const float*)d_in[36];
    const float* cg1_ad = (const float*)d_in[37];
    const float* cg2_Ws = (const float*)d_in[38];
    const float* cg2_Wd = (const float*)d_in[39];
    const float* cg2_as = (const float*)d_in[40];
    const float* cg2_ad = (const float*)d_in[41];
    const float* sa_W  = (const float*)d_in[42];
    const float* sa_b  = (const float*)d_in[43];
    const float* sa_v  = (const float*)d_in[44];
    const float* gate_W = (const float*)d_in[45];
    const float* gate_b = (const float*)d_in[46];
    const float* ww_W  = (const float*)d_in[47];
    const float* ww_b  = (const float*)d_in[48];
    float* out = (float*)d_out;

    // ---- workspace carve
    char* p = (char*)d_ws;
    auto alloc = [&](size_t bytes) -> void* {
        void* r = (void*)p;
        p += (bytes + 255) & ~(size_t)255;
        return r;
    };
    int* g_off  = (int*)alloc((Nq + 1) * 4);
    int* bn_off = (int*)alloc((Nq + 1) * 4);
    int* bw_off = (int*)alloc((NEWSq + 1) * 4);
    int* g_src  = (int*)alloc(Eq * 4);
    int* bn_src = (int*)alloc(BEq * 4);
    int* bw_src = (int*)alloc(BEq * 4);
    int* cnt    = (int*)alloc(Nq * 4);
    int* cur    = (int*)alloc(Nq * 4);

    float* wscore  = (float*)alloc(WVOCq * 4);
    float* UTraw   = (float*)alloc((size_t)Bq * Hq * 128 * 4);
    float* UT3     = (float*)alloc((size_t)Bq * Hq * 128 * 4);
    float* news1   = (float*)alloc((size_t)NEWSq * 128 * 4);
    float* NC1     = (float*)alloc((size_t)NEWSq * 128 * 4);
    float* news2   = (float*)alloc((size_t)NEWSq * 128 * 4);
    float* NC2     = (float*)alloc((size_t)NEWSq * 128 * 4);
    float* newsS1  = (float*)alloc((size_t)NEWSq * 128 * 4);   // vb / hs_news
    float* newsS2  = (float*)alloc((size_t)NEWSq * 128 * 4);   // hd_news
    float* v0      = (float*)alloc((size_t)Nq * 128 * 4);
    float* v1      = (float*)alloc((size_t)Nq * 128 * 4);
    float* nc1     = (float*)alloc((size_t)Nq * 128 * 4);
    float* v2      = (float*)alloc((size_t)Nq * 128 * 4);
    float* nc2     = (float*)alloc((size_t)Nq * 128 * 4);
    float* nodeS1  = (float*)alloc((size_t)Nq * 128 * 4);      // qb / h / hs_node / Ttmp
    float* nodeS2  = (float*)alloc((size_t)Nq * 128 * 4);      // kb / hd_node
    float* es_node = (float*)alloc(Nq * 4);
    float* ed_node = (float*)alloc(Nq * 4);
    float* es_news = (float*)alloc(NEWSq * 4);
    float* ed_news = (float*)alloc(NEWSq * 4);
    float* gate    = (float*)alloc(Nq * 4);
    float* score_bh = (float*)alloc(Bq * Hq * 4);
    float* user_vec = (float*)alloc(Bq * 128 * 4);
    float* pooled   = (float*)alloc((size_t)Bq * 6 * 128 * 4);

    float* qb = nodeS1;   // aliases (temporally disjoint)
    float* kb = nodeS2;
    float* vb = newsS1;

    const int MH = Bq * Hq;  // 6400

    // ---- CSR: graph edges by dst (N segments)
    hipMemsetAsync(cnt, 0, Nq * 4, stream);
    k_count<<<(Eq + 255) / 256, 256, 0, stream>>>(ei_dst, cnt, Eq);
    k_scan<<<1, 1024, 0, stream>>>(cnt, g_off, Nq);
    hipMemcpyAsync(cur, g_off, Nq * 4, hipMemcpyDeviceToDevice, stream);
    k_scatter<<<(Eq + 255) / 256, 256, 0, stream>>>(ei_src, ei_dst, cur, g_src, Eq);
    // ---- CSR: bi edges by node dst
    hipMemsetAsync(cnt, 0, Nq * 4, stream);
    k_count<<<(BEq + 255) / 256, 256, 0, stream>>>(bi_node, cnt, BEq);
    k_scan<<<1, 1024, 0, stream>>>(cnt, bn_off, Nq);
    hipMemcpyAsync(cur, bn_off, Nq * 4, hipMemcpyDeviceToDevice, stream);
    k_scatter<<<(BEq + 255) / 256, 256, 0, stream>>>(bi_news, bi_node, cur, bn_src, BEq);
    // ---- CSR: bi edges by news dst (reversed)
    hipMemsetAsync(cnt, 0, NEWSq * 4, stream);
    k_count<<<(BEq + 255) / 256, 256, 0, stream>>>(bi_news, cnt, BEq);
    k_scan<<<1, 1024, 0, stream>>>(cnt, bw_off, NEWSq);
    hipMemcpyAsync(cur, bw_off, NEWSq * 4, hipMemcpyDeviceToDevice, stream);
    k_scatter<<<(BEq + 255) / 256, 256, 0, stream>>>(bi_node, bi_news, cur, bw_src, BEq);

    // ---- titles
    k_word_score<<<WVOCq / WPB, 128, 0, stream>>>(word_emb, te_W, te_b, te_v, wscore, WVOCq);
    k_title_pool<<<Bq * Sq, 128, 0, stream>>>(title_tok, wscore, word_emb,
            hist_seqs, hist_lens, pos_seq, pos_len, neg_seqs, neg_lens, UTraw, news1);
    // ---- node embeddings
    k_embed<<<(Nq * 128 + 255) / 256, 256, 0, stream>>>(nodes, ent_emb, v0, Nq);

    // ---- attn1 (user titles -> news1 user slots)
    k_matmul128<<<MH / MMR, 256, 0, stream>>>(UTraw, ue1_Wq, qb, MH);
    k_matmul128<<<MH / MMR, 256, 0, stream>>>(UTraw, ue1_Wk, kb, MH);
    k_matmul128<<<MH / MMR, 256, 0, stream>>>(UTraw, ue1_Wv, vb, MH);
    k_self_attn<<<Bq, 256, 0, stream>>>(qb, kb, vb, news1, Sq * 128);

    // ---- GAT 1: v1 = gat(v0)
    k_matmul128<<<Nq / MMR, 256, 0, stream>>>(v0, g1_W, nodeS1, Nq);
    k_dot1<<<Nq, 128, 0, stream>>>(nodeS1, g1_as, es_node, nullptr);
    k_dot1<<<Nq, 128, 0, stream>>>(nodeS1, g1_ad, ed_node, nullptr);
    k_edge_agg<<<Nq, 128, 0, stream>>>(g_off, g_src, es_node, ed_node, nodeS1, nullptr, v1, 0);

    // ---- cross 1 (news1, v1, cg1): node update -> nc1
    k_matmul128<<<NEWSq / MMR, 256, 0, stream>>>(news1, cg1_Ws, newsS1, NEWSq);
    k_matmul128<<<Nq / MMR, 256, 0, stream>>>(v1, cg1_Wd, nodeS2, Nq);
    k_dot1<<<NEWSq, 128, 0, stream>>>(newsS1, cg1_as, es_news, nullptr);
    k_dot1<<<Nq, 128, 0, stream>>>(nodeS2, cg1_ad, ed_node, nullptr);
    k_edge_agg<<<Nq, 128, 0, stream>>>(bn_off, bn_src, es_news, ed_node, newsS1, v1, nc1, 1);
    //          news update -> NC1
    k_matmul128<<<Nq / MMR, 256, 0, stream>>>(v1, cg1_Ws, nodeS1, Nq);
    k_matmul128<<<NEWSq / MMR, 256, 0, stream>>>(news1, cg1_Wd, newsS2, NEWSq);
    k_dot1<<<Nq, 128, 0, stream>>>(nodeS1, cg1_as, es_node, nullptr);
    k_dot1<<<NEWSq, 128, 0, stream>>>(newsS2, cg1_ad, ed_news, nullptr);
    k_edge_agg<<<NEWSq, 128, 0, stream>>>(bw_off, bw_src, es_node, ed_news, nodeS1, news1, NC1, 1);

    // ---- attn2 (NC1 user slots -> news2 user slots), copy targets
    k_extract_user<<<(MH * 128 + 255) / 256, 256, 0, stream>>>(NC1, UTraw);
    k_matmul128<<<MH / MMR, 256, 0, stream>>>(UTraw, ue2_Wq, qb, MH);
    k_matmul128<<<MH / MMR, 256, 0, stream>>>(UTraw, ue2_Wk, kb, MH);
    k_matmul128<<<MH / MMR, 256, 0, stream>>>(UTraw, ue2_Wv, vb, MH);
    k_self_attn<<<Bq, 256, 0, stream>>>(qb, kb, vb, news2, Sq * 128);
    k_copy_targets<<<(Bq * NEG1q * 128 + 255) / 256, 256, 0, stream>>>(NC1, news2);

    // ---- GAT 2: v2 = gat(nc1)
    k_matmul128<<<Nq / MMR, 256, 0, stream>>>(nc1, g2_W, nodeS1, Nq);
    k_dot1<<<Nq, 128, 0, stream>>>(nodeS1, g2_as, es_node, nullptr);
    k_dot1<<<Nq, 128, 0, stream>>>(nodeS1, g2_ad, ed_node, nullptr);
    k_edge_agg<<<Nq, 128, 0, stream>>>(g_off, g_src, es_node, ed_node, nodeS1, nullptr, v2, 0);

    // ---- cross 2 (news2, v2, cg2): node update -> nc2
    k_matmul128<<<NEWSq / MMR, 256, 0, stream>>>(news2, cg2_Ws, newsS1, NEWSq);
    k_matmul128<<<Nq / MMR, 256, 0, stream>>>(v2, cg2_Wd, nodeS2, Nq);
    k_dot1<<<NEWSq, 128, 0, stream>>>(newsS1, cg2_as, es_news, nullptr);
    k_dot1<<<Nq, 128, 0, stream>>>(nodeS2, cg2_ad, ed_node, nullptr);
    k_edge_agg<<<Nq, 128, 0, stream>>>(bn_off, bn_src, es_news, ed_node, newsS1, v2, nc2, 1);
    //          news update -> NC2
    k_matmul128<<<Nq / MMR, 256, 0, stream>>>(v2, cg2_Ws, nodeS1, Nq);
    k_matmul128<<<NEWSq / MMR, 256, 0, stream>>>(news2, cg2_Wd, newsS2, NEWSq);
    k_dot1<<<Nq, 128, 0, stream>>>(nodeS1, cg2_as, es_node, nullptr);
    k_dot1<<<NEWSq, 128, 0, stream>>>(newsS2, cg2_ad, ed_news, nullptr);
    k_edge_agg<<<NEWSq, 128, 0, stream>>>(bw_off, bw_src, es_node, ed_news, nodeS1, news2, NC2, 1);

    // ---- attn3 (NC2 user slots -> UT3)
    k_extract_user<<<(MH * 128 + 255) / 256, 256, 0, stream>>>(NC2, UTraw);
    k_matmul128<<<MH / MMR, 256, 0, stream>>>(UTraw, ue3_Wq, qb, MH);
    k_matmul128<<<MH / MMR, 256, 0, stream>>>(UTraw, ue3_Wk, kb, MH);
    k_matmul128<<<MH / MMR, 256, 0, stream>>>(UTraw, ue3_Wv, vb, MH);
    k_self_attn<<<Bq, 256, 0, stream>>>(qb, kb, vb, UT3, Hq * 128);

    // ---- user_vec = attend_pool(UT3, sa)
    k_matmul128<<<MH / MMR, 256, 0, stream>>>(UT3, sa_W, nodeS1, MH);
    k_tanh_dot<<<MH, 128, 0, stream>>>(nodeS1, sa_b, sa_v, score_bh);
    k_user_pool<<<Bq, 128, 0, stream>>>(UT3, score_bh, user_vec);

    // ---- mask pool on nc2
    k_dot1<<<Nq, 128, 0, stream>>>(nc2, gate_W, gate, gate_b);
    k_mask_pool<<<Bq * 6, 128, 0, stream>>>(nc2, gate, hist_mask, pos_mask, neg_masks, pooled);

    // ---- final gated scores
    k_final<<<Bq * NEG1q, 128, 0, stream>>>(pooled, user_vec, NC2, ww_W, ww_b, out);
}

// Round 2
// 1046.471 us; speedup vs baseline: 1.5260x; 1.5260x over previous
//
#include <hip/hip_runtime.h>
#include <math.h>

#define Bq    128
#define Dq    128
#define Hq    50
#define NEGq  4
#define Lq    30
#define Sq    55      // H + 1 + NEG
#define NPGq  80
#define Nq    10240   // B * NPG
#define Eq    163840  // N * 16
#define NEWSq 7040    // B * S
#define BEq   28160   // NEWS * 4
#define WVOCq 50000
#define NEG1q 5

__device__ __forceinline__ float leaky_f(float x) { return x > 0.f ? x : 0.2f * x; }

// ---------------------------------------------------------------- CSR build
__global__ void k_count(const int* __restrict__ dst, int* __restrict__ cnt, int ne) {
    int e = blockIdx.x * blockDim.x + threadIdx.x;
    if (e < ne) atomicAdd(&cnt[dst[e]], 1);
}

__global__ __launch_bounds__(1024) void k_scan(const int* __restrict__ cnt, int* __restrict__ off, int n) {
    __shared__ int part[1024];
    int tid = threadIdx.x;
    int chunk = (n + 1023) >> 10;
    int s0 = tid * chunk;
    int s1 = s0 + chunk; if (s1 > n) s1 = n;
    int s = 0;
    for (int i = s0; i < s1; ++i) s += cnt[i];
    part[tid] = s;
    __syncthreads();
    for (int d = 1; d < 1024; d <<= 1) {
        int v = (tid >= d) ? part[tid - d] : 0;
        __syncthreads();
        part[tid] += v;
        __syncthreads();
    }
    int base = (tid > 0) ? part[tid - 1] : 0;
    for (int i = s0; i < s1; ++i) { off[i] = base; base += cnt[i]; }
    if (tid == 0) off[n] = part[1023];
}

__global__ void k_scatter(const int* __restrict__ src, const int* __restrict__ dst,
                          int* __restrict__ cur, int* __restrict__ out_src, int ne) {
    int e = blockIdx.x * blockDim.x + threadIdx.x;
    if (e < ne) {
        int slot = atomicAdd(&cur[dst[e]], 1);
        out_src[slot] = src[e];
    }
}

// ---------------------------------------------------------------- gathers
__global__ void k_embed(const int* __restrict__ nodes, const float* __restrict__ ent,
                        float* __restrict__ out, int n) {
    int i = blockIdx.x * blockDim.x + threadIdx.x;
    if (i < n * 128) {
        int r = i >> 7, d = i & 127;
        out[i] = ent[(long)nodes[r] * 128 + d];
    }
}

// ---------------------------------------------------------------- register-blocked matmul (f64 acc)
// Block: 256 threads = 32 col-groups (4 cols each) x 8 row-groups (4 rows each)
// Tile: 32 rows x 128 cols.  K staged in two 64-halves. LDS = 32KB(W) + 8KB(A) = 40KB.
// MODE 0: C store only
// MODE 1: C store + o0[r]=C.q0, o1[r]=C.q1
// MODE 2: o0[r] = sum_j tanh(C[r][j]+q0[j])*q1[j]   (no C store)
// MODE 3: C store + o0[r]=C.q0
// MODE 4: o0[r]=C.q0 only (no C store)
#define MMROWS 32
template<int MODE>
__global__ __launch_bounds__(256) void k_mm(const float* __restrict__ A,
        const float* __restrict__ W, float* __restrict__ C, int M,
        const float* __restrict__ q0, const float* __restrict__ q1,
        float* __restrict__ o0, float* __restrict__ o1) {
    __shared__ float sW[64 * 128];        // 32 KB: one K-half of W
    __shared__ float sA[MMROWS][64];      // 8 KB: A tile K-half
    int tid = threadIdx.x;
    int tx = tid & 31;                    // col group -> j0 = tx*4
    int ty = tid >> 5;                    // row group -> rows r0 + ty*4 + rr
    int r0 = blockIdx.x * MMROWS;
    int j0 = tx * 4;

    double acc[4][4];
#pragma unroll
    for (int rr = 0; rr < 4; ++rr)
#pragma unroll
        for (int cc = 0; cc < 4; ++cc) acc[rr][cc] = 0.0;

    for (int kh = 0; kh < 2; ++kh) {
        __syncthreads();
        const float4* W4 = (const float4*)(W + kh * 64 * 128);
        float4* sW4 = (float4*)sW;
#pragma unroll
        for (int i = tid; i < 64 * 32; i += 256) sW4[i] = W4[i];
#pragma unroll
        for (int i = tid; i < MMROWS * 16; i += 256) {
            int r = i >> 4, c4 = i & 15;
            int rr = r0 + r;
            float4 v = (rr < M) ? ((const float4*)(A + (long)rr * 128 + kh * 64))[c4]
                                : make_float4(0.f, 0.f, 0.f, 0.f);
            *(float4*)&sA[r][c4 * 4] = v;
        }
        __syncthreads();
#pragma unroll 2
        for (int k = 0; k < 64; k += 4) {
            float4 w0 = *(const float4*)&sW[(k + 0) * 128 + j0];
            float4 w1 = *(const float4*)&sW[(k + 1) * 128 + j0];
            float4 w2 = *(const float4*)&sW[(k + 2) * 128 + j0];
            float4 w3 = *(const float4*)&sW[(k + 3) * 128 + j0];
            float4 a0 = *(const float4*)&sA[ty * 4 + 0][k];
            float4 a1 = *(const float4*)&sA[ty * 4 + 1][k];
            float4 a2 = *(const float4*)&sA[ty * 4 + 2][k];
            float4 a3 = *(const float4*)&sA[ty * 4 + 3][k];
            const float4 av[4] = {a0, a1, a2, a3};
            const float4 wv[4] = {w0, w1, w2, w3};
#pragma unroll
            for (int rr = 0; rr < 4; ++rr) {
                const float ae[4] = {av[rr].x, av[rr].y, av[rr].z, av[rr].w};
#pragma unroll
                for (int kk = 0; kk < 4; ++kk) {
                    double a = (double)ae[kk];
                    acc[rr][0] += a * (double)wv[kk].x;
                    acc[rr][1] += a * (double)wv[kk].y;
                    acc[rr][2] += a * (double)wv[kk].z;
                    acc[rr][3] += a * (double)wv[kk].w;
                }
            }
        }
    }

    // ---- epilogue
    if constexpr (MODE == 0 || MODE == 1 || MODE == 3) {
#pragma unroll
        for (int rr = 0; rr < 4; ++rr) {
            int r = r0 + ty * 4 + rr;
            if (r < M) {
                float4 o = make_float4((float)acc[rr][0], (float)acc[rr][1],
                                       (float)acc[rr][2], (float)acc[rr][3]);
                *(float4*)&C[(long)r * 128 + j0] = o;
            }
        }
    }
    if constexpr (MODE == 1 || MODE == 3 || MODE == 4) {
        float q0c[4], q1c[4];
#pragma unroll
        for (int cc = 0; cc < 4; ++cc) {
            q0c[cc] = q0[j0 + cc];
            if constexpr (MODE == 1) q1c[cc] = q1[j0 + cc];
        }
#pragma unroll
        for (int rr = 0; rr < 4; ++rr) {
            int r = r0 + ty * 4 + rr;
            double d0 = 0.0, d1 = 0.0;
#pragma unroll
            for (int cc = 0; cc < 4; ++cc) {
                double c = (double)(float)acc[rr][cc];   // f32-rounded C, exact vs ref
                d0 += c * (double)q0c[cc];
                if constexpr (MODE == 1) d1 += c * (double)q1c[cc];
            }
            for (int o = 16; o > 0; o >>= 1) {
                d0 += __shfl_xor(d0, o);
                if constexpr (MODE == 1) d1 += __shfl_xor(d1, o);
            }
            if ((tid & 31) == 0 && r < M) {
                o0[r] = (float)d0;
                if constexpr (MODE == 1) o1[r] = (float)d1;
            }
        }
    }
    if constexpr (MODE == 2) {
        float q0c[4], q1c[4];
#pragma unroll
        for (int cc = 0; cc < 4; ++cc) { q0c[cc] = q0[j0 + cc]; q1c[cc] = q1[j0 + cc]; }
#pragma unroll
        for (int rr = 0; rr < 4; ++rr) {
            int r = r0 + ty * 4 + rr;
            double s = 0.0;
#pragma unroll
            for (int cc = 0; cc < 4; ++cc) {
                float t = (float)acc[rr][cc] + q0c[cc];
                s += tanh((double)t) * (double)q1c[cc];
            }
            for (int o = 16; o > 0; o >>= 1) s += __shfl_xor(s, o);
            if ((tid & 31) == 0 && r < M) o0[r] = (float)s;
        }
    }
}

// ---------------------------------------------------------------- title pooling
__global__ __launch_bounds__(128) void k_title_pool(
        const int* __restrict__ title_tok, const float* __restrict__ wscore,
        const float* __restrict__ wemb,
        const int* __restrict__ hist_seqs, const int* __restrict__ hist_lens,
        const int* __restrict__ pos_seq, const int* __restrict__ pos_len,
        const int* __restrict__ neg_seqs, const int* __restrict__ neg_lens,
        float* __restrict__ UTraw, float* __restrict__ news1) {
    int t = blockIdx.x;
    int b = t / Sq, s = t % Sq;
    int nid, len; float* dst;
    if (s < Hq)       { nid = hist_seqs[b * Hq + s]; len = hist_lens[b * Hq + s]; dst = UTraw + (long)(b * Hq + s) * 128; }
    else if (s == Hq) { nid = pos_seq[b];            len = pos_len[b];            dst = news1 + (long)t * 128; }
    else { int g = s - Hq - 1; nid = neg_seqs[b * NEGq + g]; len = neg_lens[b * NEGq + g]; dst = news1 + (long)t * 128; }

    __shared__ int tok[Lq];
    __shared__ float wgt[Lq];
    __shared__ double sden;
    int tid = threadIdx.x;
    if (tid < Lq) tok[tid] = title_tok[(long)nid * Lq + tid];
    __syncthreads();
    if (tid == 0) {
        float mx = -1e30f;
        for (int l = 0; l < len; ++l) { float sc = wscore[tok[l]]; wgt[l] = sc; if (sc > mx) mx = sc; }
        double den = 0.0;
        for (int l = 0; l < len; ++l) {
            float e = (float)exp((double)(wgt[l] - mx));
            wgt[l] = e; den += (double)e;
        }
        sden = den;
    }
    __syncthreads();
    double den = sden;
    double acc = 0.0;
    for (int l = 0; l < len; ++l)
        acc += (double)wgt[l] * (double)wemb[(long)tok[l] * 128 + tid];
    dst[tid] = (float)(acc / den);
}

// ---------------------------------------------------------------- row . vec (+ optional scalar bias ptr)
__global__ __launch_bounds__(128) void k_dot1(const float* __restrict__ X, const float* __restrict__ a,
                                              float* __restrict__ o, const float* __restrict__ bptr) {
    __shared__ double red[128];
    int n = blockIdx.x, tid = threadIdx.x;
    red[tid] = (double)X[(long)n * 128 + tid] * (double)a[tid];
    __syncthreads();
    for (int d = 64; d > 0; d >>= 1) { if (tid < d) red[tid] += red[tid + d]; __syncthreads(); }
    if (tid == 0) {
        float dotf = (float)red[0];
        if (bptr) dotf += bptr[0];
        o[n] = dotf;
    }
}

// ---------------------------------------------------------------- GAT / cross-GAT aggregation
#define MAXK 256
__global__ __launch_bounds__(128) void k_edge_agg(
        const int* __restrict__ off, const int* __restrict__ srcs,
        const float* __restrict__ es, const float* __restrict__ ed,
        const float* __restrict__ Hsrc, const float* __restrict__ Xdst,
        float* __restrict__ Out, int mode) {
    int n = blockIdx.x, tid = threadIdx.x;
    int s0 = off[n], k = off[n + 1] - s0;
    float* outp = Out + (long)n * 128;
    if (k == 0) {
        outp[tid] = mode ? Xdst[(long)n * 128 + tid] : 0.f;  // elu(0)=0 (+residual)
        return;
    }
    __shared__ int   sSrc[MAXK];
    __shared__ float sE[MAXK];
    __shared__ float sX[MAXK];
    __shared__ float redf[128];
    __shared__ double redd[128];
    float edn = ed[n];
    float mloc = -1e30f;
    for (int j = tid; j < k; j += 128) {
        int sidx = srcs[s0 + j];
        float e = leaky_f(es[sidx] + edn);
        if (j < MAXK) { sSrc[j] = sidx; sE[j] = e; }
        if (e > mloc) mloc = e;
    }
    redf[tid] = mloc; __syncthreads();
    for (int d = 64; d > 0; d >>= 1) { if (tid < d) redf[tid] = fmaxf(redf[tid], redf[tid + d]); __syncthreads(); }
    float m = redf[0];
    double dloc = 0.0;
    for (int j = tid; j < k; j += 128) {
        float e = (j < MAXK) ? sE[j] : leaky_f(es[srcs[s0 + j]] + edn);
        float ex = (float)exp((double)(e - m));
        if (j < MAXK) sX[j] = ex;
        dloc += (double)ex;
    }
    redd[tid] = dloc; __syncthreads();
    for (int d = 64; d > 0; d >>= 1) { if (tid < d) redd[tid] += redd[tid + d]; __syncthreads(); }
    double den = redd[0] + 1e-16;
    double acc = 0.0;
    for (int j = 0; j < k; ++j) {
        float ex; int sidx;
        if (j < MAXK) { ex = sX[j]; sidx = sSrc[j]; }
        else { sidx = srcs[s0 + j]; float e = leaky_f(es[sidx] + edn); ex = (float)exp((double)(e - m)); }
        float alpha = (float)((double)ex / den);
        acc += (double)alpha * (double)Hsrc[(long)sidx * 128 + tid];
    }
    float v = (float)acc;
    float o = (v > 0.f) ? v : (float)expm1((double)v);
    if (mode) o += Xdst[(long)n * 128 + tid];
    outp[tid] = o;
}

// ---------------------------------------------------------------- self-attention (one block per batch)
__global__ __launch_bounds__(256) void k_self_attn(const float* __restrict__ Q, const float* __restrict__ K,
                                                   const float* __restrict__ V, float* __restrict__ Out,
                                                   int ob_stride) {
    __shared__ float sK[Hq * 129];
    __shared__ float sV[Hq * 128];
    __shared__ float sQr[4][128];
    __shared__ float sEx[4][Hq];
    __shared__ double sDen[4];
    const double SQRTD = (double)11.3137085f;  // f32(sqrt(128))
    int b = blockIdx.x;
    int tid = threadIdx.x;
    int wv = tid >> 6, lane = tid & 63;
    const float* Kb = K + (long)b * Hq * 128;
    const float* Vb = V + (long)b * Hq * 128;
    const float* Qb = Q + (long)b * Hq * 128;
    for (int idx = tid; idx < Hq * 128; idx += 256) {
        int r = idx >> 7, i = idx & 127;
        sK[r * 129 + i] = Kb[idx];
        sV[idx] = Vb[idx];
    }
    __syncthreads();
    for (int rbase = 0; rbase < Hq; rbase += 4) {
        int r = rbase + wv;
        bool active = (r < Hq);
        __syncthreads();
        for (int idx = tid; idx < 4 * 128; idx += 256) {
            int rw = idx >> 7, i = idx & 127;
            int rr = rbase + rw;
            sQr[rw][i] = (rr < Hq) ? Qb[(long)rr * 128 + i] : 0.f;
        }
        __syncthreads();
        float sval = -1e30f;
        if (active && lane < Hq) {
            const float* q = sQr[wv];
            const float* kc = &sK[lane * 129];
            double acc = 0.0;
#pragma unroll 8
            for (int i = 0; i < 128; ++i) acc += (double)q[i] * (double)kc[i];
            sval = (float)(acc / SQRTD);
        }
        float mm = sval;
        for (int o = 32; o > 0; o >>= 1) mm = fmaxf(mm, __shfl_xor(mm, o));
        float ex = (active && lane < Hq) ? (float)exp((double)(sval - mm)) : 0.f;
        double dsum = (double)ex;
        for (int o = 32; o > 0; o >>= 1) dsum += __shfl_xor(dsum, o);
        if (active && lane < Hq) sEx[wv][lane] = ex;
        if (active && lane == 0) sDen[wv] = dsum;
        __syncthreads();
        if (active) {
            double den = sDen[wv];
            const float* exr = sEx[wv];
            double a0 = 0.0, a1 = 0.0;
            for (int c = 0; c < Hq; ++c) {
                double w = (double)exr[c];
                a0 += w * (double)sV[c * 128 + lane];
                a1 += w * (double)sV[c * 128 + lane + 64];
            }
            float* op = Out + (long)b * ob_stride + (long)r * 128;
            op[lane] = (float)(a0 / den);
            op[lane + 64] = (float)(a1 / den);
        }
    }
}

// ---------------------------------------------------------------- copies
__global__ void k_extract_user(const float* __restrict__ NC, float* __restrict__ UT) {
    int idx = blockIdx.x * blockDim.x + threadIdx.x;
    if (idx < Bq * Hq * 128) {
        int d = idx & 127, rh = idx >> 7;
        int b = rh / Hq, h = rh % Hq;
        UT[idx] = NC[((long)(b * Sq + h)) * 128 + d];
    }
}
__global__ void k_copy_targets(const float* __restrict__ NC, float* __restrict__ news2) {
    int idx = blockIdx.x * blockDim.x + threadIdx.x;
    if (idx < Bq * NEG1q * 128) {
        int d = idx & 127, rt = idx >> 7;
        int b = rt / NEG1q, s = Hq + rt % NEG1q;
        long o = ((long)(b * Sq + s)) * 128 + d;
        news2[o] = NC[o];
    }
}

// ---------------------------------------------------------------- masked pooling
__global__ __launch_bounds__(128) void k_mask_pool(const float* __restrict__ X, const float* __restrict__ gate,
        const int* __restrict__ hist_mask, const int* __restrict__ pos_mask, const int* __restrict__ neg_masks,
        float* __restrict__ pooled) {
    int blk = blockIdx.x;
    int b = blk / 6, s = blk % 6;
    int tid = threadIdx.x;
    __shared__ float sEx[NPGq];
    __shared__ float redf[128];
    __shared__ double redd[128];
    int base = b * NPGq;
    float logit = -1e30f; int mk = 0;
    if (tid < NPGq) {
        int n = base + tid;
        mk = (s == 0) ? hist_mask[n] : (s == 1) ? pos_mask[n] : neg_masks[n * NEGq + (s - 2)];
        logit = (mk > 0) ? gate[n] : -1000000000.0f;
    }
    redf[tid] = logit; __syncthreads();
    for (int d = 64; d > 0; d >>= 1) { if (tid < d) redf[tid] = fmaxf(redf[tid], redf[tid + d]); __syncthreads(); }
    float mx = redf[0];
    float ex = 0.f;
    if (tid < NPGq && mk > 0) ex = (float)exp((double)(logit - mx));
    if (tid < NPGq) sEx[tid] = ex;
    redd[tid] = (double)ex; __syncthreads();
    for (int d = 64; d > 0; d >>= 1) { if (tid < d) redd[tid] += redd[tid + d]; __syncthreads(); }
    double den = redd[0] + 1e-16;
    double acc = 0.0;
    for (int n = 0; n < NPGq; ++n)
        acc += (double)sEx[n] * (double)X[((long)(base + n)) * 128 + tid];
    pooled[(long)blk * 128 + tid] = (float)(acc / den);
}

// ---------------------------------------------------------------- user final pool (softmax over H)
__global__ __launch_bounds__(128) void k_user_pool(const float* __restrict__ UT3, const float* __restrict__ score,
                                                   float* __restrict__ uvec) {
    int b = blockIdx.x, tid = threadIdx.x;
    __shared__ float sEx[Hq];
    __shared__ float redf[128];
    __shared__ double redd[128];
    float sv = (tid < Hq) ? score[b * Hq + tid] : -1e30f;
    redf[tid] = sv; __syncthreads();
    for (int d = 64; d > 0; d >>= 1) { if (tid < d) redf[tid] = fmaxf(redf[tid], redf[tid + d]); __syncthreads(); }
    float mx = redf[0];
    float ex = (tid < Hq) ? (float)exp((double)(sv - mx)) : 0.f;
    if (tid < Hq) sEx[tid] = ex;
    redd[tid] = (double)ex; __syncthreads();
    for (int d = 64; d > 0; d >>= 1) { if (tid < d) redd[tid] += redd[tid + d]; __syncthreads(); }
    double den = redd[0];
    double acc = 0.0;
    for (int h = 0; h < Hq; ++h)
        acc += (double)sEx[h] * (double)UT3[((long)(b * Hq + h)) * 128 + tid];
    uvec[(long)b * 128 + tid] = (float)(acc / den);
}

// ---------------------------------------------------------------- final gated score
__global__ __launch_bounds__(128) void k_final(const float* __restrict__ pooled, const float* __restrict__ uvec,
        const float* __restrict__ NC2, const float* __restrict__ wwW, const float* __restrict__ wwb,
        float* __restrict__ out) {
    int blk = blockIdx.x;
    int b = blk / NEG1q, g = blk % NEG1q;
    int tid = threadIdx.x;
    __shared__ double redd[128];
    const float* ug = pooled + (long)(b * 6 + 0) * 128;
    const float* tg = pooled + (long)(b * 6 + 1 + g) * 128;
    const float* ut = uvec + (long)b * 128;
    const float* tt = NC2 + (long)(b * Sq + Hq + g) * 128;
    double w0 = (double)wwW[tid], w1 = (double)wwW[128 + tid];

    redd[tid] = (double)ug[tid] * w0 + (double)ut[tid] * w1;
    __syncthreads();
    for (int d = 64; d > 0; d >>= 1) { if (tid < d) redd[tid] += redd[tid + d]; __syncthreads(); }
    float su = (float)redd[0] + wwb[0];
    float uwf = (float)(1.0 / (1.0 + exp(-(double)su)));
    __syncthreads();

    redd[tid] = (double)tg[tid] * w0 + (double)tt[tid] * w1;
    __syncthreads();
    for (int d = 64; d > 0; d >>= 1) { if (tid < d) redd[tid] += redd[tid + d]; __syncthreads(); }
    float st = (float)redd[0] + wwb[0];
    float twf = (float)(1.0 / (1.0 + exp(-(double)st)));
    __syncthreads();

    float uh = uwf * ug[tid] + (1.f - uwf) * ut[tid];
    float th = twf * tg[tid] + (1.f - twf) * tt[tid];
    redd[tid] = (double)uh * (double)th;
    __syncthreads();
    for (int d = 64; d > 0; d >>= 1) { if (tid < d) redd[tid] += redd[tid + d]; __syncthreads(); }
    if (tid == 0) out[blk] = (float)redd[0];
}

// ================================================================ launch
extern "C" void kernel_launch(void* const* d_in, const int* in_sizes, int n_in,
                              void* d_out, int out_size, void* d_ws, size_t ws_size,
                              hipStream_t stream) {
    // ---- inputs
    const int*   nodes      = (const int*)d_in[0];
    const int*   ei_src     = (const int*)d_in[1];
    const int*   ei_dst     = ei_src + Eq;
    const int*   bi_news    = (const int*)d_in[2];   // bi_edge_index[0]: news ids
    const int*   bi_node    = bi_news + BEq;         // bi_edge_index[1]: node ids
    const int*   hist_mask  = (const int*)d_in[4];
    const int*   pos_mask   = (const int*)d_in[5];
    const int*   neg_masks  = (const int*)d_in[6];
    const int*   hist_seqs  = (const int*)d_in[7];
    const int*   hist_lens  = (const int*)d_in[8];
    const int*   pos_seq    = (const int*)d_in[9];
    const int*   pos_len    = (const int*)d_in[10];
    const int*   neg_seqs   = (const int*)d_in[11];
    const int*   neg_lens   = (const int*)d_in[12];
    const int*   title_tok  = (const int*)d_in[13];
    const float* ent_emb    = (const float*)d_in[14];
    const float* word_emb   = (const float*)d_in[15];
    const float* te_W  = (const float*)d_in[16];
    const float* te_b  = (const float*)d_in[17];
    const float* te_v  = (const float*)d_in[18];
    const float* ue1_Wq = (const float*)d_in[19];
    const float* ue1_Wk = (const float*)d_in[20];
    const float* ue1_Wv = (const float*)d_in[21];
    const float* ue2_Wq = (const float*)d_in[22];
    const float* ue2_Wk = (const float*)d_in[23];
    const float* ue2_Wv = (const float*)d_in[24];
    const float* ue3_Wq = (const float*)d_in[25];
    const float* ue3_Wk = (const float*)d_in[26];
    const float* ue3_Wv = (const float*)d_in[27];
    const float* g1_W  = (const float*)d_in[28];
    const float* g1_as = (const float*)d_in[29];
    const float* g1_ad = (const float*)d_in[30];
    const float* g2_W  = (const float*)d_in[31];
    const float* g2_as = (const float*)d_in[32];
    const float* g2_ad = (const float*)d_in[33];
    const float* cg1_Ws = (const float*)d_in[34];
    const float* cg1_Wd = (const float*)d_in[35];
    const float* cg1_as = (const float*)d_in[36];
    const float* cg1_ad = (const float*)d_in[37];
    const float* cg2_Ws = (const float*)d_in[38];
    const float* cg2_Wd = (const float*)d_in[39];
    const float* cg2_as = (const float*)d_in[40];
    const float* cg2_ad = (const float*)d_in[41];
    const float* sa_W  = (const float*)d_in[42];
    const float* sa_b  = (const float*)d_in[43];
    const float* sa_v  = (const float*)d_in[44];
    const float* gate_W = (const float*)d_in[45];
    const float* gate_b = (const float*)d_in[46];
    const float* ww_W  = (const float*)d_in[47];
    const float* ww_b  = (const float*)d_in[48];
    float* out = (float*)d_out;

    // ---- workspace carve
    char* p = (char*)d_ws;
    auto alloc = [&](size_t bytes) -> void* {
        void* r = (void*)p;
        p += (bytes + 255) & ~(size_t)255;
        return r;
    };
    int* g_off  = (int*)alloc((Nq + 1) * 4);
    int* bn_off = (int*)alloc((Nq + 1) * 4);
    int* bw_off = (int*)alloc((NEWSq + 1) * 4);
    int* g_src  = (int*)alloc(Eq * 4);
    int* bn_src = (int*)alloc(BEq * 4);
    int* bw_src = (int*)alloc(BEq * 4);
    int* cnt    = (int*)alloc(Nq * 4);
    int* cur    = (int*)alloc(Nq * 4);

    float* wscore  = (float*)alloc(WVOCq * 4);
    float* UTraw   = (float*)alloc((size_t)Bq * Hq * 128 * 4);
    float* UT3     = (float*)alloc((size_t)Bq * Hq * 128 * 4);
    float* news1   = (float*)alloc((size_t)NEWSq * 128 * 4);
    float* NC1     = (float*)alloc((size_t)NEWSq * 128 * 4);
    float* news2   = (float*)alloc((size_t)NEWSq * 128 * 4);
    float* NC2     = (float*)alloc((size_t)NEWSq * 128 * 4);
    float* newsS1  = (float*)alloc((size_t)NEWSq * 128 * 4);   // vb / hs_news
    float* v0      = (float*)alloc((size_t)Nq * 128 * 4);
    float* v1      = (float*)alloc((size_t)Nq * 128 * 4);
    float* nc1     = (float*)alloc((size_t)Nq * 128 * 4);
    float* v2      = (float*)alloc((size_t)Nq * 128 * 4);
    float* nc2     = (float*)alloc((size_t)Nq * 128 * 4);
    float* nodeS1  = (float*)alloc((size_t)Nq * 128 * 4);      // qb / h / hs_node
    float* nodeS2  = (float*)alloc((size_t)Nq * 128 * 4);      // kb
    float* es_node = (float*)alloc(Nq * 4);
    float* ed_node = (float*)alloc(Nq * 4);
    float* es_news = (float*)alloc(NEWSq * 4);
    float* ed_news = (float*)alloc(NEWSq * 4);
    float* gate    = (float*)alloc(Nq * 4);
    float* score_bh = (float*)alloc(Bq * Hq * 4);
    float* user_vec = (float*)alloc(Bq * 128 * 4);
    float* pooled   = (float*)alloc((size_t)Bq * 6 * 128 * 4);

    float* qb = nodeS1;   // aliases (temporally disjoint)
    float* kb = nodeS2;
    float* vb = newsS1;

    const int MH = Bq * Hq;  // 6400
    auto mmg = [](int M) { return (M + MMROWS - 1) / MMROWS; };

    // ---- CSR: graph edges by dst (N segments)
    hipMemsetAsync(cnt, 0, Nq * 4, stream);
    k_count<<<(Eq + 255) / 256, 256, 0, stream>>>(ei_dst, cnt, Eq);
    k_scan<<<1, 1024, 0, stream>>>(cnt, g_off, Nq);
    hipMemcpyAsync(cur, g_off, Nq * 4, hipMemcpyDeviceToDevice, stream);
    k_scatter<<<(Eq + 255) / 256, 256, 0, stream>>>(ei_src, ei_dst, cur, g_src, Eq);
    // ---- CSR: bi edges by node dst
    hipMemsetAsync(cnt, 0, Nq * 4, stream);
    k_count<<<(BEq + 255) / 256, 256, 0, stream>>>(bi_node, cnt, BEq);
    k_scan<<<1, 1024, 0, stream>>>(cnt, bn_off, Nq);
    hipMemcpyAsync(cur, bn_off, Nq * 4, hipMemcpyDeviceToDevice, stream);
    k_scatter<<<(BEq + 255) / 256, 256, 0, stream>>>(bi_news, bi_node, cur, bn_src, BEq);
    // ---- CSR: bi edges by news dst (reversed)
    hipMemsetAsync(cnt, 0, NEWSq * 4, stream);
    k_count<<<(BEq + 255) / 256, 256, 0, stream>>>(bi_news, cnt, BEq);
    k_scan<<<1, 1024, 0, stream>>>(cnt, bw_off, NEWSq);
    hipMemcpyAsync(cur, bw_off, NEWSq * 4, hipMemcpyDeviceToDevice, stream);
    k_scatter<<<(BEq + 255) / 256, 256, 0, stream>>>(bi_node, bi_news, cur, bw_src, BEq);

    // ---- titles: per-word score = tanh(word_emb@te_W + te_b)@te_v  (fused, no T store)
    k_mm<2><<<mmg(WVOCq), 256, 0, stream>>>(word_emb, te_W, nullptr, WVOCq, te_b, te_v, wscore, nullptr);
    k_title_pool<<<Bq * Sq, 128, 0, stream>>>(title_tok, wscore, word_emb,
            hist_seqs, hist_lens, pos_seq, pos_len, neg_seqs, neg_lens, UTraw, news1);
    // ---- node embeddings
    k_embed<<<(Nq * 128 + 255) / 256, 256, 0, stream>>>(nodes, ent_emb, v0, Nq);

    // ---- attn1 (user titles -> news1 user slots)
    k_mm<0><<<mmg(MH), 256, 0, stream>>>(UTraw, ue1_Wq, qb, MH, nullptr, nullptr, nullptr, nullptr);
    k_mm<0><<<mmg(MH), 256, 0, stream>>>(UTraw, ue1_Wk, kb, MH, nullptr, nullptr, nullptr, nullptr);
    k_mm<0><<<mmg(MH), 256, 0, stream>>>(UTraw, ue1_Wv, vb, MH, nullptr, nullptr, nullptr, nullptr);
    k_self_attn<<<Bq, 256, 0, stream>>>(qb, kb, vb, news1, Sq * 128);

    // ---- GAT 1: v1 = gat(v0)   (matmul + both attention dots fused)
    k_mm<1><<<mmg(Nq), 256, 0, stream>>>(v0, g1_W, nodeS1, Nq, g1_as, g1_ad, es_node, ed_node);
    k_edge_agg<<<Nq, 128, 0, stream>>>(g_off, g_src, es_node, ed_node, nodeS1, nullptr, v1, 0);

    // ---- cross 1 (news1, v1, cg1): node update -> nc1
    k_mm<3><<<mmg(NEWSq), 256, 0, stream>>>(news1, cg1_Ws, newsS1, NEWSq, cg1_as, nullptr, es_news, nullptr);
    k_mm<4><<<mmg(Nq), 256, 0, stream>>>(v1, cg1_Wd, nullptr, Nq, cg1_ad, nullptr, ed_node, nullptr);
    k_edge_agg<<<Nq, 128, 0, stream>>>(bn_off, bn_src, es_news, ed_node, newsS1, v1, nc1, 1);
    //          news update -> NC1
    k_mm<3><<<mmg(Nq), 256, 0, stream>>>(v1, cg1_Ws, nodeS1, Nq, cg1_as, nullptr, es_node, nullptr);
    k_mm<4><<<mmg(NEWSq), 256, 0, stream>>>(news1, cg1_Wd, nullptr, NEWSq, cg1_ad, nullptr, ed_news, nullptr);
    k_edge_agg<<<NEWSq, 128, 0, stream>>>(bw_off, bw_src, es_node, ed_news, nodeS1, news1, NC1, 1);

    // ---- attn2 (NC1 user slots -> news2 user slots), copy targets
    k_extract_user<<<(MH * 128 + 255) / 256, 256, 0, stream>>>(NC1, UTraw);
    k_mm<0><<<mmg(MH), 256, 0, stream>>>(UTraw, ue2_Wq, qb, MH, nullptr, nullptr, nullptr, nullptr);
    k_mm<0><<<mmg(MH), 256, 0, stream>>>(UTraw, ue2_Wk, kb, MH, nullptr, nullptr, nullptr, nullptr);
    k_mm<0><<<mmg(MH), 256, 0, stream>>>(UTraw, ue2_Wv, vb, MH, nullptr, nullptr, nullptr, nullptr);
    k_self_attn<<<Bq, 256, 0, stream>>>(qb, kb, vb, news2, Sq * 128);
    k_copy_targets<<<(Bq * NEG1q * 128 + 255) / 256, 256, 0, stream>>>(NC1, news2);

    // ---- GAT 2: v2 = gat(nc1)
    k_mm<1><<<mmg(Nq), 256, 0, stream>>>(nc1, g2_W, nodeS1, Nq, g2_as, g2_ad, es_node, ed_node);
    k_edge_agg<<<Nq, 128, 0, stream>>>(g_off, g_src, es_node, ed_node, nodeS1, nullptr, v2, 0);

    // ---- cross 2 (news2, v2, cg2): node update -> nc2
    k_mm<3><<<mmg(NEWSq), 256, 0, stream>>>(news2, cg2_Ws, newsS1, NEWSq, cg2_as, nullptr, es_news, nullptr);
    k_mm<4><<<mmg(Nq), 256, 0, stream>>>(v2, cg2_Wd, nullptr, Nq, cg2_ad, nullptr, ed_node, nullptr);
    k_edge_agg<<<Nq, 128, 0, stream>>>(bn_off, bn_src, es_news, ed_node, newsS1, v2, nc2, 1);
    //          news update -> NC2
    k_mm<3><<<mmg(Nq), 256, 0, stream>>>(v2, cg2_Ws, nodeS1, Nq, cg2_as, nullptr, es_node, nullptr);
    k_mm<4><<<mmg(NEWSq), 256, 0, stream>>>(news2, cg2_Wd, nullptr, NEWSq, cg2_ad, nullptr, ed_news, nullptr);
    k_edge_agg<<<NEWSq, 128, 0, stream>>>(bw_off, bw_src, es_node, ed_news, nodeS1, news2, NC2, 1);

    // ---- attn3 (NC2 user slots -> UT3)
    k_extract_user<<<(MH * 128 + 255) / 256, 256, 0, stream>>>(NC2, UTraw);
    k_mm<0><<<mmg(MH), 256, 0, stream>>>(UTraw, ue3_Wq, qb, MH, nullptr, nullptr, nullptr, nullptr);
    k_mm<0><<<mmg(MH), 256, 0, stream>>>(UTraw, ue3_Wk, kb, MH, nullptr, nullptr, nullptr, nullptr);
    k_mm<0><<<mmg(MH), 256, 0, stream>>>(UTraw, ue3_Wv, vb, MH, nullptr, nullptr, nullptr, nullptr);
    k_self_attn<<<Bq, 256, 0, stream>>>(qb, kb, vb, UT3, Hq * 128);

    // ---- user_vec = attend_pool(UT3, sa)  (fused tanh-dot epilogue)
    k_mm<2><<<mmg(MH), 256, 0, stream>>>(UT3, sa_W, nullptr, MH, sa_b, sa_v, score_bh, nullptr);
    k_user_pool<<<Bq, 128, 0, stream>>>(UT3, score_bh, user_vec);

    // ---- mask pool on nc2
    k_dot1<<<Nq, 128, 0, stream>>>(nc2, gate_W, gate, gate_b);
    k_mask_pool<<<Bq * 6, 128, 0, stream>>>(nc2, gate, hist_mask, pos_mask, neg_masks, pooled);

    // ---- final gated scores
    k_final<<<Bq * NEG1q, 128, 0, stream>>>(pooled, user_vec, NC2, ww_W, ww_b, out);
}

// Round 3
// 922.845 us; speedup vs baseline: 1.7305x; 1.1340x over previous
//
#include <hip/hip_runtime.h>
#include <math.h>

#define Bq    128
#define Dq    128
#define Hq    50
#define NEGq  4
#define Lq    30
#define Sq    55      // H + 1 + NEG
#define NPGq  80
#define Nq    10240   // B * NPG
#define Eq    163840  // N * 16
#define NEWSq 7040    // B * S
#define BEq   28160   // NEWS * 4
#define WVOCq 50000
#define NEG1q 5

__device__ __forceinline__ float leaky_f(float x) { return x > 0.f ? x : 0.2f * x; }

// ---------------------------------------------------------------- CSR build (fused x3)
__global__ void k_count_all(const int* __restrict__ ei_dst, const int* __restrict__ bi_node,
                            const int* __restrict__ bi_news,
                            int* __restrict__ cg, int* __restrict__ cbn, int* __restrict__ cbw) {
    int e = blockIdx.x * blockDim.x + threadIdx.x;
    if (e < Eq) atomicAdd(&cg[ei_dst[e]], 1);
    else if (e < Eq + BEq) atomicAdd(&cbn[bi_node[e - Eq]], 1);
    else if (e < Eq + 2 * BEq) atomicAdd(&cbw[bi_news[e - Eq - BEq]], 1);
}

__global__ __launch_bounds__(1024) void k_scan3(
        const int* __restrict__ cg, const int* __restrict__ cbn, const int* __restrict__ cbw,
        int* __restrict__ og, int* __restrict__ obn, int* __restrict__ obw,
        int* __restrict__ curg, int* __restrict__ curbn, int* __restrict__ curbw) {
    __shared__ int part[1024];
    const int* cnt; int* off; int* cur; int n;
    if (blockIdx.x == 0)      { cnt = cg;  off = og;  cur = curg;  n = Nq; }
    else if (blockIdx.x == 1) { cnt = cbn; off = obn; cur = curbn; n = Nq; }
    else                      { cnt = cbw; off = obw; cur = curbw; n = NEWSq; }
    int tid = threadIdx.x;
    int chunk = (n + 1023) >> 10;
    int s0 = tid * chunk;
    int s1 = s0 + chunk; if (s1 > n) s1 = n;
    int s = 0;
    for (int i = s0; i < s1; ++i) s += cnt[i];
    part[tid] = s;
    __syncthreads();
    for (int d = 1; d < 1024; d <<= 1) {
        int v = (tid >= d) ? part[tid - d] : 0;
        __syncthreads();
        part[tid] += v;
        __syncthreads();
    }
    int base = (tid > 0) ? part[tid - 1] : 0;
    for (int i = s0; i < s1; ++i) { off[i] = base; cur[i] = base; base += cnt[i]; }
    if (tid == 0) off[n] = part[1023];
}

__global__ void k_scatter_all(const int* __restrict__ ei_src, const int* __restrict__ ei_dst,
                              const int* __restrict__ bi_news, const int* __restrict__ bi_node,
                              int* __restrict__ curg, int* __restrict__ curbn, int* __restrict__ curbw,
                              int* __restrict__ g_out, int* __restrict__ bn_out, int* __restrict__ bw_out) {
    int e = blockIdx.x * blockDim.x + threadIdx.x;
    if (e < Eq) {
        int slot = atomicAdd(&curg[ei_dst[e]], 1);
        g_out[slot] = ei_src[e];
    } else if (e < Eq + BEq) {
        int i = e - Eq;
        int slot = atomicAdd(&curbn[bi_node[i]], 1);
        bn_out[slot] = bi_news[i];
    } else if (e < Eq + 2 * BEq) {
        int i = e - Eq - BEq;
        int slot = atomicAdd(&curbw[bi_news[i]], 1);
        bw_out[slot] = bi_node[i];
    }
}

// ---------------------------------------------------------------- gathers
__global__ void k_embed(const int* __restrict__ nodes, const float* __restrict__ ent,
                        float* __restrict__ out, int n) {
    int i = blockIdx.x * blockDim.x + threadIdx.x;
    if (i < n * 32) {
        int r = i >> 5, d = i & 31;
        ((float4*)out)[i] = ((const float4*)(ent + (long)nodes[r] * 128))[d];
    }
}

// ---------------------------------------------------------------- matmul core
// Tile: 32 rows x 128 cols, 256 threads, 4x4 micro-tile.
// f32 FMA chains over 4-deep k-chunks, f64 chunk accumulation.
// K staged in 4 slices of 32 -> LDS = 16KB(W) + 4KB(A) = 20KB -> 8 blocks/CU cap.
// MODE 0: C store only
// MODE 1: C store + o0[r]=C.q0, o1[r]=C.q1
// MODE 2: o0[r] = sum_j tanh(C[r][j]+q0[j])*q1[j]   (no C store)
// MODE 3: C store + o0[r]=C.q0
// MODE 4: o0[r]=C.q0 only (no C store)
#define MMROWS 32
template<int MODE>
__device__ __forceinline__ void mm_body(float* sW, float (*sA)[32],
        const float* __restrict__ A, const float* __restrict__ W, float* __restrict__ C,
        int M, int r0, const float* __restrict__ q0, const float* __restrict__ q1,
        float* __restrict__ o0, float* __restrict__ o1) {
    int tid = threadIdx.x;
    int tx = tid & 31;                    // col group -> j0 = tx*4
    int ty = tid >> 5;                    // row group -> rows r0 + ty*4 + rr
    int j0 = tx * 4;

    double acc[4][4];
#pragma unroll
    for (int rr = 0; rr < 4; ++rr)
#pragma unroll
        for (int cc = 0; cc < 4; ++cc) acc[rr][cc] = 0.0;

    for (int ks = 0; ks < 4; ++ks) {
        __syncthreads();
        const float4* W4 = (const float4*)(W + ks * 32 * 128);
        float4* sW4 = (float4*)sW;
#pragma unroll
        for (int i = tid; i < 32 * 32; i += 256) sW4[i] = W4[i];
        {
            int r = tid >> 3, c4 = tid & 7;     // 32 rows x 8 float4
            int rr = r0 + r;
            float4 v = (rr < M) ? *(const float4*)(A + (long)rr * 128 + ks * 32 + c4 * 4)
                                : make_float4(0.f, 0.f, 0.f, 0.f);
            *(float4*)&sA[r][c4 * 4] = v;
        }
        __syncthreads();
#pragma unroll
        for (int k = 0; k < 32; k += 4) {
            float4 w0 = *(const float4*)&sW[(k + 0) * 128 + j0];
            float4 w1 = *(const float4*)&sW[(k + 1) * 128 + j0];
            float4 w2 = *(const float4*)&sW[(k + 2) * 128 + j0];
            float4 w3 = *(const float4*)&sW[(k + 3) * 128 + j0];
            const float we[4][4] = {{w0.x, w1.x, w2.x, w3.x},
                                    {w0.y, w1.y, w2.y, w3.y},
                                    {w0.z, w1.z, w2.z, w3.z},
                                    {w0.w, w1.w, w2.w, w3.w}};
#pragma unroll
            for (int rr = 0; rr < 4; ++rr) {
                float4 a = *(const float4*)&sA[ty * 4 + rr][k];
#pragma unroll
                for (int cc = 0; cc < 4; ++cc) {
                    float p = a.x * we[cc][0];
                    p = fmaf(a.y, we[cc][1], p);
                    p = fmaf(a.z, we[cc][2], p);
                    p = fmaf(a.w, we[cc][3], p);
                    acc[rr][cc] += (double)p;
                }
            }
        }
    }

    // ---- epilogue
    if constexpr (MODE == 0 || MODE == 1 || MODE == 3) {
#pragma unroll
        for (int rr = 0; rr < 4; ++rr) {
            int r = r0 + ty * 4 + rr;
            if (r < M) {
                float4 o = make_float4((float)acc[rr][0], (float)acc[rr][1],
                                       (float)acc[rr][2], (float)acc[rr][3]);
                *(float4*)&C[(long)r * 128 + j0] = o;
            }
        }
    }
    if constexpr (MODE == 1 || MODE == 3 || MODE == 4) {
        float q0c[4], q1c[4];
#pragma unroll
        for (int cc = 0; cc < 4; ++cc) {
            q0c[cc] = q0[j0 + cc];
            if constexpr (MODE == 1) q1c[cc] = q1[j0 + cc];
        }
#pragma unroll
        for (int rr = 0; rr < 4; ++rr) {
            int r = r0 + ty * 4 + rr;
            double d0 = 0.0, d1 = 0.0;
#pragma unroll
            for (int cc = 0; cc < 4; ++cc) {
                double c = (double)(float)acc[rr][cc];   // f32-rounded C
                d0 += c * (double)q0c[cc];
                if constexpr (MODE == 1) d1 += c * (double)q1c[cc];
            }
            for (int o = 16; o > 0; o >>= 1) {
                d0 += __shfl_xor(d0, o);
                if constexpr (MODE == 1) d1 += __shfl_xor(d1, o);
            }
            if ((tid & 31) == 0 && r < M) {
                o0[r] = (float)d0;
                if constexpr (MODE == 1) o1[r] = (float)d1;
            }
        }
    }
    if constexpr (MODE == 2) {
        float q0c[4], q1c[4];
#pragma unroll
        for (int cc = 0; cc < 4; ++cc) { q0c[cc] = q0[j0 + cc]; q1c[cc] = q1[j0 + cc]; }
#pragma unroll
        for (int rr = 0; rr < 4; ++rr) {
            int r = r0 + ty * 4 + rr;
            double s = 0.0;
#pragma unroll
            for (int cc = 0; cc < 4; ++cc) {
                float t = (float)acc[rr][cc] + q0c[cc];
                s += tanh((double)t) * (double)q1c[cc];
            }
            for (int o = 16; o > 0; o >>= 1) s += __shfl_xor(s, o);
            if ((tid & 31) == 0 && r < M) o0[r] = (float)s;
        }
    }
}

template<int MODE>
__global__ __launch_bounds__(256) void k_mm(const float* __restrict__ A,
        const float* __restrict__ W, float* __restrict__ C, int M,
        const float* __restrict__ q0, const float* __restrict__ q1,
        float* __restrict__ o0, float* __restrict__ o1) {
    __shared__ float sW[32 * 128];
    __shared__ float sA[MMROWS][32];
    mm_body<MODE>(sW, sA, A, W, C, M, blockIdx.x * MMROWS, q0, q1, o0, o1);
}

// fused triple matmul (same A, three W/C) — for Q,K,V
__global__ __launch_bounds__(256) void k_mm3(const float* __restrict__ A,
        const float* __restrict__ W0, const float* __restrict__ W1, const float* __restrict__ W2,
        float* __restrict__ C0, float* __restrict__ C1, float* __restrict__ C2, int M, int nb) {
    __shared__ float sW[32 * 128];
    __shared__ float sA[MMROWS][32];
    int w = blockIdx.x / nb, blk = blockIdx.x % nb;
    const float* W = (w == 0) ? W0 : (w == 1) ? W1 : W2;
    float* C = (w == 0) ? C0 : (w == 1) ? C1 : C2;
    mm_body<0>(sW, sA, A, W, C, M, blk * MMROWS, nullptr, nullptr, nullptr, nullptr);
}

// ---------------------------------------------------------------- title pooling
__global__ __launch_bounds__(128) void k_title_pool(
        const int* __restrict__ title_tok, const float* __restrict__ wscore,
        const float* __restrict__ wemb,
        const int* __restrict__ hist_seqs, const int* __restrict__ hist_lens,
        const int* __restrict__ pos_seq, const int* __restrict__ pos_len,
        const int* __restrict__ neg_seqs, const int* __restrict__ neg_lens,
        float* __restrict__ UTraw, float* __restrict__ news1) {
    int t = blockIdx.x;
    int b = t / Sq, s = t % Sq;
    int nid, len; float* dst;
    if (s < Hq)       { nid = hist_seqs[b * Hq + s]; len = hist_lens[b * Hq + s]; dst = UTraw + (long)(b * Hq + s) * 128; }
    else if (s == Hq) { nid = pos_seq[b];            len = pos_len[b];            dst = news1 + (long)t * 128; }
    else { int g = s - Hq - 1; nid = neg_seqs[b * NEGq + g]; len = neg_lens[b * NEGq + g]; dst = news1 + (long)t * 128; }

    __shared__ int tok[Lq];
    __shared__ float wgt[Lq];
    __shared__ double sden;
    int tid = threadIdx.x;
    if (tid < Lq) tok[tid] = title_tok[(long)nid * Lq + tid];
    __syncthreads();
    if (tid < 64) {   // first wave does the softmax over len<=30 lanes
        float sc = (tid < len) ? wscore[tok[tid]] : -1e30f;
        float mx = sc;
        for (int o = 32; o > 0; o >>= 1) mx = fmaxf(mx, __shfl_xor(mx, o));
        float e = (tid < len) ? (float)exp((double)(sc - mx)) : 0.f;
        if (tid < Lq) wgt[tid] = e;
        double ds = (double)e;
        for (int o = 32; o > 0; o >>= 1) ds += __shfl_xor(ds, o);
        if (tid == 0) sden = ds;
    }
    __syncthreads();
    double den = sden;
    double acc = 0.0;
    for (int l = 0; l < len; ++l)
        acc += (double)wgt[l] * (double)wemb[(long)tok[l] * 128 + tid];
    dst[tid] = (float)(acc / den);
}

// ---------------------------------------------------------------- GAT / cross-GAT aggregation
#define MAXK 256
__global__ __launch_bounds__(128) void k_edge_agg(
        const int* __restrict__ off, const int* __restrict__ srcs,
        const float* __restrict__ es, const float* __restrict__ ed,
        const float* __restrict__ Hsrc, const float* __restrict__ Xdst,
        float* __restrict__ Out, int mode,
        const float* __restrict__ gW, const float* __restrict__ gb, float* __restrict__ gout) {
    int n = blockIdx.x, tid = threadIdx.x;
    int s0 = off[n], k = off[n + 1] - s0;
    __shared__ int    sSrc[MAXK];
    __shared__ float  sX[MAXK];
    __shared__ float  redf[128];
    __shared__ double redd[128];
    __shared__ double sPart[4][128];
    float o;
    if (k == 0) {
        o = mode ? Xdst[(long)n * 128 + tid] : 0.f;   // elu(0)=0 (+residual)
    } else {
        float edn = ed[n];
        float mloc = -1e30f;
        for (int j = tid; j < k; j += 128) {
            int sidx = srcs[s0 + j];
            float e = leaky_f(es[sidx] + edn);
            if (j < MAXK) { sSrc[j] = sidx; sX[j] = e; }
            mloc = fmaxf(mloc, e);
        }
        redf[tid] = mloc; __syncthreads();
        for (int d = 64; d > 0; d >>= 1) { if (tid < d) redf[tid] = fmaxf(redf[tid], redf[tid + d]); __syncthreads(); }
        float m = redf[0];
        double dloc = 0.0;
        for (int j = tid; j < k; j += 128) {
            float e = (j < MAXK) ? sX[j] : leaky_f(es[srcs[s0 + j]] + edn);
            float ex = (float)exp((double)(e - m));
            if (j < MAXK) sX[j] = ex;
            dloc += (double)ex;
        }
        redd[tid] = dloc; __syncthreads();
        for (int d = 64; d > 0; d >>= 1) { if (tid < d) redd[tid] += redd[tid + d]; __syncthreads(); }
        double den = redd[0] + 1e-16;
        // weighted aggregation: 4-way j-parallel, float4 d-slices, f64 partials
        int jj = tid >> 5, dg = (tid & 31) * 4;
        double a0 = 0.0, a1 = 0.0, a2 = 0.0, a3 = 0.0;
        for (int j = jj; j < k; j += 4) {
            float ex; int sidx;
            if (j < MAXK) { ex = sX[j]; sidx = sSrc[j]; }
            else { sidx = srcs[s0 + j]; float e = leaky_f(es[sidx] + edn); ex = (float)exp((double)(e - m)); }
            float alpha = (float)((double)ex / den);
            float4 h = *(const float4*)&Hsrc[(long)sidx * 128 + dg];
            a0 += (double)alpha * (double)h.x;
            a1 += (double)alpha * (double)h.y;
            a2 += (double)alpha * (double)h.z;
            a3 += (double)alpha * (double)h.w;
        }
        sPart[jj][dg + 0] = a0; sPart[jj][dg + 1] = a1;
        sPart[jj][dg + 2] = a2; sPart[jj][dg + 3] = a3;
        __syncthreads();
        double v = sPart[0][tid] + sPart[1][tid] + sPart[2][tid] + sPart[3][tid];
        float vf = (float)v;
        o = (vf > 0.f) ? vf : (float)expm1((double)vf);
        if (mode) o += Xdst[(long)n * 128 + tid];
    }
    Out[(long)n * 128 + tid] = o;
    if (gout) {   // fused gate = f32(dot(out_row, gW)) + gb
        redd[tid] = (double)o * (double)gW[tid];
        __syncthreads();
        for (int d = 64; d > 0; d >>= 1) { if (tid < d) redd[tid] += redd[tid + d]; __syncthreads(); }
        if (tid == 0) gout[n] = (float)redd[0] + gb[0];
    }
}

// ---------------------------------------------------------------- self-attention (one block per batch)
__global__ __launch_bounds__(256) void k_self_attn(const float* __restrict__ Q, const float* __restrict__ K,
                                                   const float* __restrict__ V, float* __restrict__ Out,
                                                   int ob_stride) {
    __shared__ float sK[Hq * 129];
    __shared__ float sV[Hq * 128];
    __shared__ float sQr[4][128];
    __shared__ float sEx[4][Hq];
    __shared__ double sDen[4];
    const double SQRTD = (double)11.3137085f;  // f32(sqrt(128))
    int b = blockIdx.x;
    int tid = threadIdx.x;
    int wv = tid >> 6, lane = tid & 63;
    const float* Kb = K + (long)b * Hq * 128;
    const float* Vb = V + (long)b * Hq * 128;
    const float* Qb = Q + (long)b * Hq * 128;
    for (int idx = tid; idx < Hq * 128; idx += 256) {
        int r = idx >> 7, i = idx & 127;
        sK[r * 129 + i] = Kb[idx];
        sV[idx] = Vb[idx];
    }
    __syncthreads();
    for (int rbase = 0; rbase < Hq; rbase += 4) {
        int r = rbase + wv;
        bool active = (r < Hq);
        __syncthreads();
        for (int idx = tid; idx < 4 * 128; idx += 256) {
            int rw = idx >> 7, i = idx & 127;
            int rr = rbase + rw;
            sQr[rw][i] = (rr < Hq) ? Qb[(long)rr * 128 + i] : 0.f;
        }
        __syncthreads();
        float sval = -1e30f;
        if (active && lane < Hq) {
            const float* q = sQr[wv];
            const float* kc = &sK[lane * 129];
            double acc = 0.0;
#pragma unroll 8
            for (int i = 0; i < 128; ++i) acc += (double)q[i] * (double)kc[i];
            sval = (float)(acc / SQRTD);
        }
        float mm = sval;
        for (int o = 32; o > 0; o >>= 1) mm = fmaxf(mm, __shfl_xor(mm, o));
        float ex = (active && lane < Hq) ? (float)exp((double)(sval - mm)) : 0.f;
        double dsum = (double)ex;
        for (int o = 32; o > 0; o >>= 1) dsum += __shfl_xor(dsum, o);
        if (active && lane < Hq) sEx[wv][lane] = ex;
        if (active && lane == 0) sDen[wv] = dsum;
        __syncthreads();
        if (active) {
            double den = sDen[wv];
            const float* exr = sEx[wv];
            double a0 = 0.0, a1 = 0.0;
            for (int c = 0; c < Hq; ++c) {
                double w = (double)exr[c];
                a0 += w * (double)sV[c * 128 + lane];
                a1 += w * (double)sV[c * 128 + lane + 64];
            }
            float* op = Out + (long)b * ob_stride + (long)r * 128;
            op[lane] = (float)(a0 / den);
            op[lane + 64] = (float)(a1 / den);
        }
    }
}

// ---------------------------------------------------------------- copies
__global__ void k_extract_user(const float* __restrict__ NC, float* __restrict__ UT) {
    int idx = blockIdx.x * blockDim.x + threadIdx.x;
    if (idx < Bq * Hq * 32) {
        int d = idx & 31, rh = idx >> 5;
        int b = rh / Hq, h = rh % Hq;
        ((float4*)UT)[idx] = ((const float4*)(NC + ((long)(b * Sq + h)) * 128))[d];
    }
}
__global__ void k_copy_targets(const float* __restrict__ NC, float* __restrict__ news2) {
    int idx = blockIdx.x * blockDim.x + threadIdx.x;
    if (idx < Bq * NEG1q * 32) {
        int d = idx & 31, rt = idx >> 5;
        int b = rt / NEG1q, s = Hq + rt % NEG1q;
        long o = ((long)(b * Sq + s)) * 32 + d;
        ((float4*)news2)[o] = ((const float4*)NC)[o];
    }
}

// ---------------------------------------------------------------- masked pooling
__global__ __launch_bounds__(128) void k_mask_pool(const float* __restrict__ X, const float* __restrict__ gate,
        const int* __restrict__ hist_mask, const int* __restrict__ pos_mask, const int* __restrict__ neg_masks,
        float* __restrict__ pooled) {
    int blk = blockIdx.x;
    int b = blk / 6, s = blk % 6;
    int tid = threadIdx.x;
    __shared__ float sEx[NPGq];
    __shared__ float redf[128];
    __shared__ double redd[128];
    int base = b * NPGq;
    float logit = -1e30f; int mk = 0;
    if (tid < NPGq) {
        int n = base + tid;
        mk = (s == 0) ? hist_mask[n] : (s == 1) ? pos_mask[n] : neg_masks[n * NEGq + (s - 2)];
        logit = (mk > 0) ? gate[n] : -1000000000.0f;
    }
    redf[tid] = logit; __syncthreads();
    for (int d = 64; d > 0; d >>= 1) { if (tid < d) redf[tid] = fmaxf(redf[tid], redf[tid + d]); __syncthreads(); }
    float mx = redf[0];
    float ex = 0.f;
    if (tid < NPGq && mk > 0) ex = (float)exp((double)(logit - mx));
    if (tid < NPGq) sEx[tid] = ex;
    redd[tid] = (double)ex; __syncthreads();
    for (int d = 64; d > 0; d >>= 1) { if (tid < d) redd[tid] += redd[tid + d]; __syncthreads(); }
    double den = redd[0] + 1e-16;
    double acc = 0.0;
    for (int n = 0; n < NPGq; ++n)
        acc += (double)sEx[n] * (double)X[((long)(base + n)) * 128 + tid];
    pooled[(long)blk * 128 + tid] = (float)(acc / den);
}

// ---------------------------------------------------------------- user final pool (softmax over H)
__global__ __launch_bounds__(128) void k_user_pool(const float* __restrict__ UT3, const float* __restrict__ score,
                                                   float* __restrict__ uvec) {
    int b = blockIdx.x, tid = threadIdx.x;
    __shared__ float sEx[Hq];
    __shared__ float redf[128];
    __shared__ double redd[128];
    float sv = (tid < Hq) ? score[b * Hq + tid] : -1e30f;
    redf[tid] = sv; __syncthreads();
    for (int d = 64; d > 0; d >>= 1) { if (tid < d) redf[tid] = fmaxf(redf[tid], redf[tid + d]); __syncthreads(); }
    float mx = redf[0];
    float ex = (tid < Hq) ? (float)exp((double)(sv - mx)) : 0.f;
    if (tid < Hq) sEx[tid] = ex;
    redd[tid] = (double)ex; __syncthreads();
    for (int d = 64; d > 0; d >>= 1) { if (tid < d) redd[tid] += redd[tid + d]; __syncthreads(); }
    double den = redd[0];
    double acc = 0.0;
    for (int h = 0; h < Hq; ++h)
        acc += (double)sEx[h] * (double)UT3[((long)(b * Hq + h)) * 128 + tid];
    uvec[(long)b * 128 + tid] = (float)(acc / den);
}

// ---------------------------------------------------------------- final gated score
__global__ __launch_bounds__(128) void k_final(const float* __restrict__ pooled, const float* __restrict__ uvec,
        const float* __restrict__ NC2, const float* __restrict__ wwW, const float* __restrict__ wwb,
        float* __restrict__ out) {
    int blk = blockIdx.x;
    int b = blk / NEG1q, g = blk % NEG1q;
    int tid = threadIdx.x;
    __shared__ double redd[128];
    const float* ug = pooled + (long)(b * 6 + 0) * 128;
    const float* tg = pooled + (long)(b * 6 + 1 + g) * 128;
    const float* ut = uvec + (long)b * 128;
    const float* tt = NC2 + (long)(b * Sq + Hq + g) * 128;
    double w0 = (double)wwW[tid], w1 = (double)wwW[128 + tid];

    redd[tid] = (double)ug[tid] * w0 + (double)ut[tid] * w1;
    __syncthreads();
    for (int d = 64; d > 0; d >>= 1) { if (tid < d) redd[tid] += redd[tid + d]; __syncthreads(); }
    float su = (float)redd[0] + wwb[0];
    float uwf = (float)(1.0 / (1.0 + exp(-(double)su)));
    __syncthreads();

    redd[tid] = (double)tg[tid] * w0 + (double)tt[tid] * w1;
    __syncthreads();
    for (int d = 64; d > 0; d >>= 1) { if (tid < d) redd[tid] += redd[tid + d]; __syncthreads(); }
    float st = (float)redd[0] + wwb[0];
    float twf = (float)(1.0 / (1.0 + exp(-(double)st)));
    __syncthreads();

    float uh = uwf * ug[tid] + (1.f - uwf) * ut[tid];
    float th = twf * tg[tid] + (1.f - twf) * tt[tid];
    redd[tid] = (double)uh * (double)th;
    __syncthreads();
    for (int d = 64; d > 0; d >>= 1) { if (tid < d) redd[tid] += redd[tid + d]; __syncthreads(); }
    if (tid == 0) out[blk] = (float)redd[0];
}

// ================================================================ launch
extern "C" void kernel_launch(void* const* d_in, const int* in_sizes, int n_in,
                              void* d_out, int out_size, void* d_ws, size_t ws_size,
                              hipStream_t stream) {
    // ---- inputs
    const int*   nodes      = (const int*)d_in[0];
    const int*   ei_src     = (const int*)d_in[1];
    const int*   ei_dst     = ei_src + Eq;
    const int*   bi_news    = (const int*)d_in[2];   // bi_edge_index[0]: news ids
    const int*   bi_node    = bi_news + BEq;         // bi_edge_index[1]: node ids
    const int*   hist_mask  = (const int*)d_in[4];
    const int*   pos_mask   = (const int*)d_in[5];
    const int*   neg_masks  = (const int*)d_in[6];
    const int*   hist_seqs  = (const int*)d_in[7];
    const int*   hist_lens  = (const int*)d_in[8];
    const int*   pos_seq    = (const int*)d_in[9];
    const int*   pos_len    = (const int*)d_in[10];
    const int*   neg_seqs   = (const int*)d_in[11];
    const int*   neg_lens   = (const int*)d_in[12];
    const int*   title_tok  = (const int*)d_in[13];
    const float* ent_emb    = (const float*)d_in[14];
    const float* word_emb   = (const float*)d_in[15];
    const float* te_W  = (const float*)d_in[16];
    const float* te_b  = (const float*)d_in[17];
    const float* te_v  = (const float*)d_in[18];
    const float* ue1_Wq = (const float*)d_in[19];
    const float* ue1_Wk = (const float*)d_in[20];
    const float* ue1_Wv = (const float*)d_in[21];
    const float* ue2_Wq = (const float*)d_in[22];
    const float* ue2_Wk = (const float*)d_in[23];
    const float* ue2_Wv = (const float*)d_in[24];
    const float* ue3_Wq = (const float*)d_in[25];
    const float* ue3_Wk = (const float*)d_in[26];
    const float* ue3_Wv = (const float*)d_in[27];
    const float* g1_W  = (const float*)d_in[28];
    const float* g1_as = (const float*)d_in[29];
    const float* g1_ad = (const float*)d_in[30];
    const float* g2_W  = (const float*)d_in[31];
    const float* g2_as = (const float*)d_in[32];
    const float* g2_ad = (const float*)d_in[33];
    const float* cg1_Ws = (const float*)d_in[34];
    const float* cg1_Wd = (const float*)d_in[35];
    const float* cg1_as = (const float*)d_in[36];
    const float* cg1_ad = (const float*)d_in[37];
    const float* cg2_Ws = (const float*)d_in[38];
    const float* cg2_Wd = (const float*)d_in[39];
    const float* cg2_as = (const float*)d_in[40];
    const float* cg2_ad = (const float*)d_in[41];
    const float* sa_W  = (const float*)d_in[42];
    const float* sa_b  = (const float*)d_in[43];
    const float* sa_v  = (const float*)d_in[44];
    const float* gate_W = (const float*)d_in[45];
    const float* gate_b = (const float*)d_in[46];
    const float* ww_W  = (const float*)d_in[47];
    const float* ww_b  = (const float*)d_in[48];
    float* out = (float*)d_out;

    // ---- workspace carve
    char* p = (char*)d_ws;
    auto alloc = [&](size_t bytes) -> void* {
        void* r = (void*)p;
        p += (bytes + 255) & ~(size_t)255;
        return r;
    };
    int* g_off  = (int*)alloc((Nq + 1) * 4);
    int* bn_off = (int*)alloc((Nq + 1) * 4);
    int* bw_off = (int*)alloc((NEWSq + 1) * 4);
    int* g_src  = (int*)alloc(Eq * 4);
    int* bn_src = (int*)alloc(BEq * 4);
    int* bw_src = (int*)alloc(BEq * 4);
    int* cnt3   = (int*)alloc((2 * Nq + NEWSq) * 4);   // cg | cbn | cbw contiguous
    int* cur3   = (int*)alloc((2 * Nq + NEWSq) * 4);
    int* cg  = cnt3, *cbn = cnt3 + Nq, *cbw = cnt3 + 2 * Nq;
    int* curg = cur3, *curbn = cur3 + Nq, *curbw = cur3 + 2 * Nq;

    float* wscore  = (float*)alloc(WVOCq * 4);
    float* UTraw   = (float*)alloc((size_t)Bq * Hq * 128 * 4);
    float* UT3     = (float*)alloc((size_t)Bq * Hq * 128 * 4);
    float* news1   = (float*)alloc((size_t)NEWSq * 128 * 4);
    float* NC1     = (float*)alloc((size_t)NEWSq * 128 * 4);
    float* news2   = (float*)alloc((size_t)NEWSq * 128 * 4);
    float* NC2     = (float*)alloc((size_t)NEWSq * 128 * 4);
    float* newsS1  = (float*)alloc((size_t)NEWSq * 128 * 4);   // vb / hs_news
    float* v0      = (float*)alloc((size_t)Nq * 128 * 4);
    float* v1      = (float*)alloc((size_t)Nq * 128 * 4);
    float* nc1     = (float*)alloc((size_t)Nq * 128 * 4);
    float* v2      = (float*)alloc((size_t)Nq * 128 * 4);
    float* nc2     = (float*)alloc((size_t)Nq * 128 * 4);
    float* nodeS1  = (float*)alloc((size_t)Nq * 128 * 4);      // qb / h / hs_node
    float* nodeS2  = (float*)alloc((size_t)Nq * 128 * 4);      // kb
    float* es_node = (float*)alloc(Nq * 4);
    float* ed_node = (float*)alloc(Nq * 4);
    float* es_news = (float*)alloc(NEWSq * 4);
    float* ed_news = (float*)alloc(NEWSq * 4);
    float* gate    = (float*)alloc(Nq * 4);
    float* score_bh = (float*)alloc(Bq * Hq * 4);
    float* user_vec = (float*)alloc(Bq * 128 * 4);
    float* pooled   = (float*)alloc((size_t)Bq * 6 * 128 * 4);

    float* qb = nodeS1;   // aliases (temporally disjoint)
    float* kb = nodeS2;
    float* vb = newsS1;

    const int MH = Bq * Hq;  // 6400
    auto mmg = [](int M) { return (M + MMROWS - 1) / MMROWS; };
    const int TOTE = Eq + 2 * BEq;

    // ---- CSR build (3 segmentations, fused)
    hipMemsetAsync(cnt3, 0, (size_t)(2 * Nq + NEWSq) * 4, stream);
    k_count_all<<<(TOTE + 255) / 256, 256, 0, stream>>>(ei_dst, bi_node, bi_news, cg, cbn, cbw);
    k_scan3<<<3, 1024, 0, stream>>>(cg, cbn, cbw, g_off, bn_off, bw_off, curg, curbn, curbw);
    k_scatter_all<<<(TOTE + 255) / 256, 256, 0, stream>>>(ei_src, ei_dst, bi_news, bi_node,
            curg, curbn, curbw, g_src, bn_src, bw_src);

    // ---- titles: per-word score = tanh(word_emb@te_W + te_b)@te_v  (fused, no T store)
    k_mm<2><<<mmg(WVOCq), 256, 0, stream>>>(word_emb, te_W, nullptr, WVOCq, te_b, te_v, wscore, nullptr);
    k_title_pool<<<Bq * Sq, 128, 0, stream>>>(title_tok, wscore, word_emb,
            hist_seqs, hist_lens, pos_seq, pos_len, neg_seqs, neg_lens, UTraw, news1);
    // ---- node embeddings
    k_embed<<<(Nq * 32 + 255) / 256, 256, 0, stream>>>(nodes, ent_emb, v0, Nq);

    // ---- attn1 (user titles -> news1 user slots)
    k_mm3<<<3 * mmg(MH), 256, 0, stream>>>(UTraw, ue1_Wq, ue1_Wk, ue1_Wv, qb, kb, vb, MH, mmg(MH));
    k_self_attn<<<Bq, 256, 0, stream>>>(qb, kb, vb, news1, Sq * 128);

    // ---- GAT 1: v1 = gat(v0)   (matmul + both attention dots fused)
    k_mm<1><<<mmg(Nq), 256, 0, stream>>>(v0, g1_W, nodeS1, Nq, g1_as, g1_ad, es_node, ed_node);
    k_edge_agg<<<Nq, 128, 0, stream>>>(g_off, g_src, es_node, ed_node, nodeS1, nullptr, v1, 0,
                                       nullptr, nullptr, nullptr);

    // ---- cross 1 (news1, v1, cg1): node update -> nc1
    k_mm<3><<<mmg(NEWSq), 256, 0, stream>>>(news1, cg1_Ws, newsS1, NEWSq, cg1_as, nullptr, es_news, nullptr);
    k_mm<4><<<mmg(Nq), 256, 0, stream>>>(v1, cg1_Wd, nullptr, Nq, cg1_ad, nullptr, ed_node, nullptr);
    k_edge_agg<<<Nq, 128, 0, stream>>>(bn_off, bn_src, es_news, ed_node, newsS1, v1, nc1, 1,
                                       nullptr, nullptr, nullptr);
    //          news update -> NC1
    k_mm<3><<<mmg(Nq), 256, 0, stream>>>(v1, cg1_Ws, nodeS1, Nq, cg1_as, nullptr, es_node, nullptr);
    k_mm<4><<<mmg(NEWSq), 256, 0, stream>>>(news1, cg1_Wd, nullptr, NEWSq, cg1_ad, nullptr, ed_news, nullptr);
    k_edge_agg<<<NEWSq, 128, 0, stream>>>(bw_off, bw_src, es_node, ed_news, nodeS1, news1, NC1, 1,
                                          nullptr, nullptr, nullptr);

    // ---- attn2 (NC1 user slots -> news2 user slots), copy targets
    k_extract_user<<<(MH * 32 + 255) / 256, 256, 0, stream>>>(NC1, UTraw);
    k_mm3<<<3 * mmg(MH), 256, 0, stream>>>(UTraw, ue2_Wq, ue2_Wk, ue2_Wv, qb, kb, vb, MH, mmg(MH));
    k_self_attn<<<Bq, 256, 0, stream>>>(qb, kb, vb, news2, Sq * 128);
    k_copy_targets<<<(Bq * NEG1q * 32 + 255) / 256, 256, 0, stream>>>(NC1, news2);

    // ---- GAT 2: v2 = gat(nc1)
    k_mm<1><<<mmg(Nq), 256, 0, stream>>>(nc1, g2_W, nodeS1, Nq, g2_as, g2_ad, es_node, ed_node);
    k_edge_agg<<<Nq, 128, 0, stream>>>(g_off, g_src, es_node, ed_node, nodeS1, nullptr, v2, 0,
                                       nullptr, nullptr, nullptr);

    // ---- cross 2 (news2, v2, cg2): node update -> nc2  (+ fused gate dot)
    k_mm<3><<<mmg(NEWSq), 256, 0, stream>>>(news2, cg2_Ws, newsS1, NEWSq, cg2_as, nullptr, es_news, nullptr);
    k_mm<4><<<mmg(Nq), 256, 0, stream>>>(v2, cg2_Wd, nullptr, Nq, cg2_ad, nullptr, ed_node, nullptr);
    k_edge_agg<<<Nq, 128, 0, stream>>>(bn_off, bn_src, es_news, ed_node, newsS1, v2, nc2, 1,
                                       gate_W, gate_b, gate);
    //          news update -> NC2
    k_mm<3><<<mmg(Nq), 256, 0, stream>>>(v2, cg2_Ws, nodeS1, Nq, cg2_as, nullptr, es_node, nullptr);
    k_mm<4><<<mmg(NEWSq), 256, 0, stream>>>(news2, cg2_Wd, nullptr, NEWSq, cg2_ad, nullptr, ed_news, nullptr);
    k_edge_agg<<<NEWSq, 128, 0, stream>>>(bw_off, bw_src, es_node, ed_news, nodeS1, news2, NC2, 1,
                                          nullptr, nullptr, nullptr);

    // ---- attn3 (NC2 user slots -> UT3)
    k_extract_user<<<(MH * 32 + 255) / 256, 256, 0, stream>>>(NC2, UTraw);
    k_mm3<<<3 * mmg(MH), 256, 0, stream>>>(UTraw, ue3_Wq, ue3_Wk, ue3_Wv, qb, kb, vb, MH, mmg(MH));
    k_self_attn<<<Bq, 256, 0, stream>>>(qb, kb, vb, UT3, Hq * 128);

    // ---- user_vec = attend_pool(UT3, sa)  (fused tanh-dot epilogue)
    k_mm<2><<<mmg(MH), 256, 0, stream>>>(UT3, sa_W, nullptr, MH, sa_b, sa_v, score_bh, nullptr);
    k_user_pool<<<Bq, 128, 0, stream>>>(UT3, score_bh, user_vec);

    // ---- mask pool on nc2 (gate already computed by fused edge_agg)
    k_mask_pool<<<Bq * 6, 128, 0, stream>>>(nc2, gate, hist_mask, pos_mask, neg_masks, pooled);

    // ---- final gated scores
    k_final<<<Bq * NEG1q, 128, 0, stream>>>(pooled, user_vec, NC2, ww_W, ww_b, out);
}

// Round 4
// 732.827 us; speedup vs baseline: 2.1792x; 1.2593x over previous
//
#include <hip/hip_runtime.h>
#include <math.h>

#define Bq    128
#define Dq    128
#define Hq    50
#define NEGq  4
#define Lq    30
#define Sq    55      // H + 1 + NEG
#define NPGq  80
#define Nq    10240   // B * NPG
#define Eq    163840  // N * 16
#define NEWSq 7040    // B * S
#define BEq   28160   // NEWS * 4
#define WVOCq 50000
#define NEG1q 5

__device__ __forceinline__ float leaky_f(float x) { return x > 0.f ? x : 0.2f * x; }

// ---------------------------------------------------------------- CSR build (fused x3)
__global__ void k_count_all(const int* __restrict__ ei_dst, const int* __restrict__ bi_node,
                            const int* __restrict__ bi_news,
                            int* __restrict__ cg, int* __restrict__ cbn, int* __restrict__ cbw) {
    int e = blockIdx.x * blockDim.x + threadIdx.x;
    if (e < Eq) atomicAdd(&cg[ei_dst[e]], 1);
    else if (e < Eq + BEq) atomicAdd(&cbn[bi_node[e - Eq]], 1);
    else if (e < Eq + 2 * BEq) atomicAdd(&cbw[bi_news[e - Eq - BEq]], 1);
}

__global__ __launch_bounds__(1024) void k_scan3(
        const int* __restrict__ cg, const int* __restrict__ cbn, const int* __restrict__ cbw,
        int* __restrict__ og, int* __restrict__ obn, int* __restrict__ obw,
        int* __restrict__ curg, int* __restrict__ curbn, int* __restrict__ curbw) {
    __shared__ int part[1024];
    const int* cnt; int* off; int* cur; int n;
    if (blockIdx.x == 0)      { cnt = cg;  off = og;  cur = curg;  n = Nq; }
    else if (blockIdx.x == 1) { cnt = cbn; off = obn; cur = curbn; n = Nq; }
    else                      { cnt = cbw; off = obw; cur = curbw; n = NEWSq; }
    int tid = threadIdx.x;
    int chunk = (n + 1023) >> 10;
    int s0 = tid * chunk;
    int s1 = s0 + chunk; if (s1 > n) s1 = n;
    int s = 0;
    for (int i = s0; i < s1; ++i) s += cnt[i];
    part[tid] = s;
    __syncthreads();
    for (int d = 1; d < 1024; d <<= 1) {
        int v = (tid >= d) ? part[tid - d] : 0;
        __syncthreads();
        part[tid] += v;
        __syncthreads();
    }
    int base = (tid > 0) ? part[tid - 1] : 0;
    for (int i = s0; i < s1; ++i) { off[i] = base; cur[i] = base; base += cnt[i]; }
    if (tid == 0) off[n] = part[1023];
}

__global__ void k_scatter_all(const int* __restrict__ ei_src, const int* __restrict__ ei_dst,
                              const int* __restrict__ bi_news, const int* __restrict__ bi_node,
                              int* __restrict__ curg, int* __restrict__ curbn, int* __restrict__ curbw,
                              int* __restrict__ g_out, int* __restrict__ bn_out, int* __restrict__ bw_out) {
    int e = blockIdx.x * blockDim.x + threadIdx.x;
    if (e < Eq) {
        int slot = atomicAdd(&curg[ei_dst[e]], 1);
        g_out[slot] = ei_src[e];
    } else if (e < Eq + BEq) {
        int i = e - Eq;
        int slot = atomicAdd(&curbn[bi_node[i]], 1);
        bn_out[slot] = bi_news[i];
    } else if (e < Eq + 2 * BEq) {
        int i = e - Eq - BEq;
        int slot = atomicAdd(&curbw[bi_news[i]], 1);
        bw_out[slot] = bi_node[i];
    }
}

// ---------------------------------------------------------------- gathers
__global__ void k_embed(const int* __restrict__ nodes, const float* __restrict__ ent,
                        float* __restrict__ out, int n) {
    int i = blockIdx.x * blockDim.x + threadIdx.x;
    if (i < n * 32) {
        int r = i >> 5, d = i & 31;
        ((float4*)out)[i] = ((const float4*)(ent + (long)nodes[r] * 128))[d];
    }
}

// ---------------------------------------------------------------- matmul core
// Tile: 32 rows x 128 cols, 256 threads, 4x4 micro-tile.
// f32 FMA chains over 16-deep k-chunks, f64 merge every 16 k.
// K staged in 4 slices of 32 -> LDS = 16KB(W) + 4KB(A) = 20KB.
// amap=1: A row r maps to user slot (r/50)*55 + r%50 (NC gather, kills extract_user).
#define MMROWS 32

#define MM4(CC, WC) \
    f[rr][CC] = fmaf(a.x, w0.WC, f[rr][CC]); \
    f[rr][CC] = fmaf(a.y, w1.WC, f[rr][CC]); \
    f[rr][CC] = fmaf(a.z, w2.WC, f[rr][CC]); \
    f[rr][CC] = fmaf(a.w, w3.WC, f[rr][CC]);

__device__ __forceinline__ void mm_compute(float* sW, float (*sA)[32],
        const float* __restrict__ A, const float* __restrict__ W,
        int M, int r0, int amap, double acc[4][4]) {
    int tid = threadIdx.x;
    int tx = tid & 31;                    // col group -> j0 = tx*4
    int ty = tid >> 5;                    // row group
    int j0 = tx * 4;
#pragma unroll
    for (int rr = 0; rr < 4; ++rr)
#pragma unroll
        for (int cc = 0; cc < 4; ++cc) acc[rr][cc] = 0.0;

    for (int ks = 0; ks < 4; ++ks) {
        __syncthreads();
        const float4* W4 = (const float4*)(W + ks * 32 * 128);
        float4* sW4 = (float4*)sW;
#pragma unroll
        for (int i = tid; i < 32 * 32; i += 256) sW4[i] = W4[i];
        {
            int r = tid >> 3, c4 = tid & 7;     // 32 rows x 8 float4
            int rr = r0 + r;
            float4 v = make_float4(0.f, 0.f, 0.f, 0.f);
            if (rr < M) {
                long pr = amap ? (long)((rr / Hq) * Sq + rr % Hq) : (long)rr;
                v = *(const float4*)(A + pr * 128 + ks * 32 + c4 * 4);
            }
            *(float4*)&sA[r][c4 * 4] = v;
        }
        __syncthreads();
#pragma unroll
        for (int half = 0; half < 2; ++half) {
            float f[4][4];
#pragma unroll
            for (int rr = 0; rr < 4; ++rr)
#pragma unroll
                for (int cc = 0; cc < 4; ++cc) f[rr][cc] = 0.f;
#pragma unroll
            for (int k4 = 0; k4 < 16; k4 += 4) {
                int k = half * 16 + k4;
                float4 w0 = *(const float4*)&sW[(k + 0) * 128 + j0];
                float4 w1 = *(const float4*)&sW[(k + 1) * 128 + j0];
                float4 w2 = *(const float4*)&sW[(k + 2) * 128 + j0];
                float4 w3 = *(const float4*)&sW[(k + 3) * 128 + j0];
#pragma unroll
                for (int rr = 0; rr < 4; ++rr) {
                    float4 a = *(const float4*)&sA[ty * 4 + rr][k];
                    MM4(0, x) MM4(1, y) MM4(2, z) MM4(3, w)
                }
            }
#pragma unroll
            for (int rr = 0; rr < 4; ++rr)
#pragma unroll
                for (int cc = 0; cc < 4; ++cc) acc[rr][cc] += (double)f[rr][cc];
        }
    }
}

// ---- generic job-table matmul: C store (opt) + row dots (opt, 1 or 2)
struct MMJob {
    const float* A; const float* W; float* C;
    const float* q0; const float* q1;
    float* o0; float* o1;
    int M; int blk_end; int amap;
};
struct MMJobs { MMJob j[4]; };

__global__ __launch_bounds__(256) void k_mm_jobs(MMJobs js) {
    __shared__ float sW[32 * 128];
    __shared__ float sA[MMROWS][32];
    int bid = blockIdx.x;
    int ji = 0, blk0 = 0;
#pragma unroll
    for (int t = 0; t < 3; ++t)
        if (bid >= js.j[t].blk_end) { ji = t + 1; blk0 = js.j[t].blk_end; }
    MMJob J = js.j[ji];
    double acc[4][4];
    mm_compute(sW, sA, J.A, J.W, J.M, (bid - blk0) * MMROWS, J.amap, acc);
    int tid = threadIdx.x, tx = tid & 31, ty = tid >> 5;
    int j0 = tx * 4;
    int r0 = (bid - blk0) * MMROWS;
    if (J.C) {
#pragma unroll
        for (int rr = 0; rr < 4; ++rr) {
            int r = r0 + ty * 4 + rr;
            if (r < J.M) {
                float4 o = make_float4((float)acc[rr][0], (float)acc[rr][1],
                                       (float)acc[rr][2], (float)acc[rr][3]);
                *(float4*)&J.C[(long)r * 128 + j0] = o;
            }
        }
    }
    if (J.o0) {
        float q0c[4], q1c[4];
        bool two = (J.q1 != nullptr);
#pragma unroll
        for (int cc = 0; cc < 4; ++cc) {
            q0c[cc] = J.q0[j0 + cc];
            q1c[cc] = two ? J.q1[j0 + cc] : 0.f;
        }
#pragma unroll
        for (int rr = 0; rr < 4; ++rr) {
            int r = r0 + ty * 4 + rr;
            double d0 = 0.0, d1 = 0.0;
#pragma unroll
            for (int cc = 0; cc < 4; ++cc) {
                double c = (double)(float)acc[rr][cc];   // f32-rounded C
                d0 += c * (double)q0c[cc];
                d1 += c * (double)q1c[cc];
            }
            for (int o = 16; o > 0; o >>= 1) {
                d0 += __shfl_xor(d0, o);
                if (two) d1 += __shfl_xor(d1, o);
            }
            if ((tid & 31) == 0 && r < J.M) {
                J.o0[r] = (float)d0;
                if (two) J.o1[r] = (float)d1;
            }
        }
    }
}

// ---- tanh-dot matmul: o0[r] = sum_j tanh(C[r][j]+q0[j])*q1[j]  (no C store)
__global__ __launch_bounds__(256) void k_mm_tanh(const float* __restrict__ A,
        const float* __restrict__ W, int M,
        const float* __restrict__ q0, const float* __restrict__ q1,
        float* __restrict__ o0) {
    __shared__ float sW[32 * 128];
    __shared__ float sA[MMROWS][32];
    double acc[4][4];
    int r0 = blockIdx.x * MMROWS;
    mm_compute(sW, sA, A, W, M, r0, 0, acc);
    int tid = threadIdx.x, tx = tid & 31, ty = tid >> 5;
    int j0 = tx * 4;
    float q0c[4], q1c[4];
#pragma unroll
    for (int cc = 0; cc < 4; ++cc) { q0c[cc] = q0[j0 + cc]; q1c[cc] = q1[j0 + cc]; }
#pragma unroll
    for (int rr = 0; rr < 4; ++rr) {
        int r = r0 + ty * 4 + rr;
        double s = 0.0;
#pragma unroll
        for (int cc = 0; cc < 4; ++cc) {
            float t = (float)acc[rr][cc] + q0c[cc];
            s += (double)tanhf(t) * (double)q1c[cc];
        }
        for (int o = 16; o > 0; o >>= 1) s += __shfl_xor(s, o);
        if ((tid & 31) == 0 && r < M) o0[r] = (float)s;
    }
}

// ---------------------------------------------------------------- title pooling
__global__ __launch_bounds__(128) void k_title_pool(
        const int* __restrict__ title_tok, const float* __restrict__ wscore,
        const float* __restrict__ wemb,
        const int* __restrict__ hist_seqs, const int* __restrict__ hist_lens,
        const int* __restrict__ pos_seq, const int* __restrict__ pos_len,
        const int* __restrict__ neg_seqs, const int* __restrict__ neg_lens,
        float* __restrict__ UTraw, float* __restrict__ news1) {
    int t = blockIdx.x;
    int b = t / Sq, s = t % Sq;
    int nid, len; float* dst;
    if (s < Hq)       { nid = hist_seqs[b * Hq + s]; len = hist_lens[b * Hq + s]; dst = UTraw + (long)(b * Hq + s) * 128; }
    else if (s == Hq) { nid = pos_seq[b];            len = pos_len[b];            dst = news1 + (long)t * 128; }
    else { int g = s - Hq - 1; nid = neg_seqs[b * NEGq + g]; len = neg_lens[b * NEGq + g]; dst = news1 + (long)t * 128; }

    __shared__ int tok[Lq];
    __shared__ float wgt[Lq];
    __shared__ double sden;
    int tid = threadIdx.x;
    if (tid < Lq) tok[tid] = title_tok[(long)nid * Lq + tid];
    __syncthreads();
    if (tid < 64) {   // first wave does the softmax over len<=30 lanes
        float sc = (tid < len) ? wscore[tok[tid]] : -1e30f;
        float mx = sc;
        for (int o = 32; o > 0; o >>= 1) mx = fmaxf(mx, __shfl_xor(mx, o));
        float e = (tid < len) ? (float)exp((double)(sc - mx)) : 0.f;
        if (tid < Lq) wgt[tid] = e;
        double ds = (double)e;
        for (int o = 32; o > 0; o >>= 1) ds += __shfl_xor(ds, o);
        if (tid == 0) sden = ds;
    }
    __syncthreads();
    double den = sden;
    double acc = 0.0;
    for (int l = 0; l < len; ++l)
        acc += (double)wgt[l] * (double)wemb[(long)tok[l] * 128 + tid];
    dst[tid] = (float)(acc / den);
}

// ---------------------------------------------------------------- GAT / cross-GAT aggregation (dual-segment)
#define MAXK 256
struct EASet {
    const int* off; const int* srcs;
    const float* es; const float* ed;
    const float* Hsrc; const float* Xdst;
    float* Out; int nseg; int mode;
};

__global__ __launch_bounds__(128) void k_edge_agg2(EASet a, EASet b,
        const float* __restrict__ gW, const float* __restrict__ gb, float* __restrict__ gout) {
    int blk = blockIdx.x, tid = threadIdx.x;
    bool isA = blk < a.nseg;
    EASet S = isA ? a : b;
    int n = isA ? blk : blk - a.nseg;
    int s0 = S.off[n], k = S.off[n + 1] - s0;
    __shared__ int    sSrc[MAXK];
    __shared__ float  sX[MAXK];
    __shared__ float  redf[128];
    __shared__ double redd[128];
    __shared__ double sPart[4][128];
    float o;
    if (k == 0) {
        o = S.mode ? S.Xdst[(long)n * 128 + tid] : 0.f;   // elu(0)=0 (+residual)
    } else {
        float edn = S.ed[n];
        float mloc = -1e30f;
        for (int j = tid; j < k; j += 128) {
            int sidx = S.srcs[s0 + j];
            float e = leaky_f(S.es[sidx] + edn);
            if (j < MAXK) { sSrc[j] = sidx; sX[j] = e; }
            mloc = fmaxf(mloc, e);
        }
        redf[tid] = mloc; __syncthreads();
        for (int d = 64; d > 0; d >>= 1) { if (tid < d) redf[tid] = fmaxf(redf[tid], redf[tid + d]); __syncthreads(); }
        float m = redf[0];
        double dloc = 0.0;
        for (int j = tid; j < k; j += 128) {
            float e = (j < MAXK) ? sX[j] : leaky_f(S.es[S.srcs[s0 + j]] + edn);
            float ex = (float)exp((double)(e - m));
            if (j < MAXK) sX[j] = ex;
            dloc += (double)ex;
        }
        redd[tid] = dloc; __syncthreads();
        for (int d = 64; d > 0; d >>= 1) { if (tid < d) redd[tid] += redd[tid + d]; __syncthreads(); }
        double den = redd[0] + 1e-16;
        // weighted aggregation: 4-way j-parallel, float4 d-slices, f64 partials
        int jj = tid >> 5, dg = (tid & 31) * 4;
        double a0 = 0.0, a1 = 0.0, a2 = 0.0, a3 = 0.0;
        for (int j = jj; j < k; j += 4) {
            float ex; int sidx;
            if (j < MAXK) { ex = sX[j]; sidx = sSrc[j]; }
            else { sidx = S.srcs[s0 + j]; float e = leaky_f(S.es[sidx] + edn); ex = (float)exp((double)(e - m)); }
            float alpha = (float)((double)ex / den);
            float4 h = *(const float4*)&S.Hsrc[(long)sidx * 128 + dg];
            a0 += (double)alpha * (double)h.x;
            a1 += (double)alpha * (double)h.y;
            a2 += (double)alpha * (double)h.z;
            a3 += (double)alpha * (double)h.w;
        }
        sPart[jj][dg + 0] = a0; sPart[jj][dg + 1] = a1;
        sPart[jj][dg + 2] = a2; sPart[jj][dg + 3] = a3;
        __syncthreads();
        double v = sPart[0][tid] + sPart[1][tid] + sPart[2][tid] + sPart[3][tid];
        float vf = (float)v;
        o = (vf > 0.f) ? vf : (float)expm1((double)vf);
        if (S.mode) o += S.Xdst[(long)n * 128 + tid];
    }
    S.Out[(long)n * 128 + tid] = o;
    if (isA && gout) {   // fused gate = f32(dot(out_row, gW)) + gb
        redd[tid] = (double)o * (double)gW[tid];
        __syncthreads();
        for (int d = 64; d > 0; d >>= 1) { if (tid < d) redd[tid] += redd[tid + d]; __syncthreads(); }
        if (tid == 0) gout[n] = (float)redd[0] + gb[0];
    }
}

// ---------------------------------------------------------------- self-attention (one block per batch)
__global__ __launch_bounds__(256) void k_self_attn(const float* __restrict__ Q, const float* __restrict__ K,
                                                   const float* __restrict__ V, float* __restrict__ Out,
                                                   int ob_stride) {
    __shared__ float sK[Hq * 129];
    __shared__ float sV[Hq * 128];
    __shared__ float sQr[4][128];
    __shared__ float sEx[4][Hq];
    __shared__ double sDen[4];
    const double SQRTD = (double)11.3137085f;  // f32(sqrt(128))
    int b = blockIdx.x;
    int tid = threadIdx.x;
    int wv = tid >> 6, lane = tid & 63;
    const float* Kb = K + (long)b * Hq * 128;
    const float* Vb = V + (long)b * Hq * 128;
    const float* Qb = Q + (long)b * Hq * 128;
    for (int idx = tid; idx < Hq * 128; idx += 256) {
        int r = idx >> 7, i = idx & 127;
        sK[r * 129 + i] = Kb[idx];
        sV[idx] = Vb[idx];
    }
    __syncthreads();
    for (int rbase = 0; rbase < Hq; rbase += 4) {
        int r = rbase + wv;
        bool active = (r < Hq);
        __syncthreads();
        for (int idx = tid; idx < 4 * 128; idx += 256) {
            int rw = idx >> 7, i = idx & 127;
            int rr = rbase + rw;
            sQr[rw][i] = (rr < Hq) ? Qb[(long)rr * 128 + i] : 0.f;
        }
        __syncthreads();
        float sval = -1e30f;
        if (active && lane < Hq) {
            const float* q = sQr[wv];
            const float* kc = &sK[lane * 129];
            double acc = 0.0;
#pragma unroll
            for (int c0 = 0; c0 < 128; c0 += 16) {
                float f = 0.f;
#pragma unroll
                for (int i = 0; i < 16; ++i) f = fmaf(q[c0 + i], kc[c0 + i], f);
                acc += (double)f;
            }
            sval = (float)(acc / SQRTD);
        }
        float mm = sval;
        for (int o = 32; o > 0; o >>= 1) mm = fmaxf(mm, __shfl_xor(mm, o));
        float ex = (active && lane < Hq) ? (float)exp((double)(sval - mm)) : 0.f;
        double dsum = (double)ex;
        for (int o = 32; o > 0; o >>= 1) dsum += __shfl_xor(dsum, o);
        if (active && lane < Hq) sEx[wv][lane] = ex;
        if (active && lane == 0) sDen[wv] = dsum;
        __syncthreads();
        if (active) {
            double den = sDen[wv];
            const float* exr = sEx[wv];
            double a0 = 0.0, a1 = 0.0;
            for (int c0 = 0; c0 < Hq; c0 += 16) {
                float f0 = 0.f, f1 = 0.f;
                int ce = (c0 + 16 < Hq) ? c0 + 16 : Hq;
                for (int c = c0; c < ce; ++c) {
                    float w = exr[c];
                    f0 = fmaf(w, sV[c * 128 + lane], f0);
                    f1 = fmaf(w, sV[c * 128 + lane + 64], f1);
                }
                a0 += (double)f0; a1 += (double)f1;
            }
            float* op = Out + (long)b * ob_stride + (long)r * 128;
            op[lane] = (float)(a0 / den);
            op[lane + 64] = (float)(a1 / den);
        }
    }
}

// ---------------------------------------------------------------- copies
__global__ void k_copy_targets(const float* __restrict__ NC, float* __restrict__ news2) {
    int idx = blockIdx.x * blockDim.x + threadIdx.x;
    if (idx < Bq * NEG1q * 32) {
        int d = idx & 31, rt = idx >> 5;
        int b = rt / NEG1q, s = Hq + rt % NEG1q;
        long o = ((long)(b * Sq + s)) * 32 + d;
        ((float4*)news2)[o] = ((const float4*)NC)[o];
    }
}

// ---------------------------------------------------------------- masked pooling
__global__ __launch_bounds__(128) void k_mask_pool(const float* __restrict__ X, const float* __restrict__ gate,
        const int* __restrict__ hist_mask, const int* __restrict__ pos_mask, const int* __restrict__ neg_masks,
        float* __restrict__ pooled) {
    int blk = blockIdx.x;
    int b = blk / 6, s = blk % 6;
    int tid = threadIdx.x;
    __shared__ float sEx[NPGq];
    __shared__ float redf[128];
    __shared__ double redd[128];
    int base = b * NPGq;
    float logit = -1e30f; int mk = 0;
    if (tid < NPGq) {
        int n = base + tid;
        mk = (s == 0) ? hist_mask[n] : (s == 1) ? pos_mask[n] : neg_masks[n * NEGq + (s - 2)];
        logit = (mk > 0) ? gate[n] : -1000000000.0f;
    }
    redf[tid] = logit; __syncthreads();
    for (int d = 64; d > 0; d >>= 1) { if (tid < d) redf[tid] = fmaxf(redf[tid], redf[tid + d]); __syncthreads(); }
    float mx = redf[0];
    float ex = 0.f;
    if (tid < NPGq && mk > 0) ex = (float)exp((double)(logit - mx));
    if (tid < NPGq) sEx[tid] = ex;
    redd[tid] = (double)ex; __syncthreads();
    for (int d = 64; d > 0; d >>= 1) { if (tid < d) redd[tid] += redd[tid + d]; __syncthreads(); }
    double den = redd[0] + 1e-16;
    double acc = 0.0;
    for (int c0 = 0; c0 < NPGq; c0 += 16) {
        float f = 0.f;
#pragma unroll
        for (int c = 0; c < 16; ++c)
            f = fmaf(sEx[c0 + c], X[((long)(base + c0 + c)) * 128 + tid], f);
        acc += (double)f;
    }
    pooled[(long)blk * 128 + tid] = (float)(acc / den);
}

// ---------------------------------------------------------------- user final pool (softmax over H)
__global__ __launch_bounds__(128) void k_user_pool(const float* __restrict__ UT3, const float* __restrict__ score,
                                                   float* __restrict__ uvec) {
    int b = blockIdx.x, tid = threadIdx.x;
    __shared__ float sEx[Hq];
    __shared__ float redf[128];
    __shared__ double redd[128];
    float sv = (tid < Hq) ? score[b * Hq + tid] : -1e30f;
    redf[tid] = sv; __syncthreads();
    for (int d = 64; d > 0; d >>= 1) { if (tid < d) redf[tid] = fmaxf(redf[tid], redf[tid + d]); __syncthreads(); }
    float mx = redf[0];
    float ex = (tid < Hq) ? (float)exp((double)(sv - mx)) : 0.f;
    if (tid < Hq) sEx[tid] = ex;
    redd[tid] = (double)ex; __syncthreads();
    for (int d = 64; d > 0; d >>= 1) { if (tid < d) redd[tid] += redd[tid + d]; __syncthreads(); }
    double den = redd[0];
    double acc = 0.0;
    for (int h = 0; h < Hq; ++h)
        acc += (double)sEx[h] * (double)UT3[((long)(b * Hq + h)) * 128 + tid];
    uvec[(long)b * 128 + tid] = (float)(acc / den);
}

// ---------------------------------------------------------------- final gated score
__global__ __launch_bounds__(128) void k_final(const float* __restrict__ pooled, const float* __restrict__ uvec,
        const float* __restrict__ NC2, const float* __restrict__ wwW, const float* __restrict__ wwb,
        float* __restrict__ out) {
    int blk = blockIdx.x;
    int b = blk / NEG1q, g = blk % NEG1q;
    int tid = threadIdx.x;
    __shared__ double redd[128];
    const float* ug = pooled + (long)(b * 6 + 0) * 128;
    const float* tg = pooled + (long)(b * 6 + 1 + g) * 128;
    const float* ut = uvec + (long)b * 128;
    const float* tt = NC2 + (long)(b * Sq + Hq + g) * 128;
    double w0 = (double)wwW[tid], w1 = (double)wwW[128 + tid];

    redd[tid] = (double)ug[tid] * w0 + (double)ut[tid] * w1;
    __syncthreads();
    for (int d = 64; d > 0; d >>= 1) { if (tid < d) redd[tid] += redd[tid + d]; __syncthreads(); }
    float su = (float)redd[0] + wwb[0];
    float uwf = (float)(1.0 / (1.0 + exp(-(double)su)));
    __syncthreads();

    redd[tid] = (double)tg[tid] * w0 + (double)tt[tid] * w1;
    __syncthreads();
    for (int d = 64; d > 0; d >>= 1) { if (tid < d) redd[tid] += redd[tid + d]; __syncthreads(); }
    float st = (float)redd[0] + wwb[0];
    float twf = (float)(1.0 / (1.0 + exp(-(double)st)));
    __syncthreads();

    float uh = uwf * ug[tid] + (1.f - uwf) * ut[tid];
    float th = twf * tg[tid] + (1.f - twf) * tt[tid];
    redd[tid] = (double)uh * (double)th;
    __syncthreads();
    for (int d = 64; d > 0; d >>= 1) { if (tid < d) redd[tid] += redd[tid + d]; __syncthreads(); }
    if (tid == 0) out[blk] = (float)redd[0];
}

// ================================================================ launch
extern "C" void kernel_launch(void* const* d_in, const int* in_sizes, int n_in,
                              void* d_out, int out_size, void* d_ws, size_t ws_size,
                              hipStream_t stream) {
    // ---- inputs
    const int*   nodes      = (const int*)d_in[0];
    const int*   ei_src     = (const int*)d_in[1];
    const int*   ei_dst     = ei_src + Eq;
    const int*   bi_news    = (const int*)d_in[2];   // bi_edge_index[0]: news ids
    const int*   bi_node    = bi_news + BEq;         // bi_edge_index[1]: node ids
    const int*   hist_mask  = (const int*)d_in[4];
    const int*   pos_mask   = (const int*)d_in[5];
    const int*   neg_masks  = (const int*)d_in[6];
    const int*   hist_seqs  = (const int*)d_in[7];
    const int*   hist_lens  = (const int*)d_in[8];
    const int*   pos_seq    = (const int*)d_in[9];
    const int*   pos_len    = (const int*)d_in[10];
    const int*   neg_seqs   = (const int*)d_in[11];
    const int*   neg_lens   = (const int*)d_in[12];
    const int*   title_tok  = (const int*)d_in[13];
    const float* ent_emb    = (const float*)d_in[14];
    const float* word_emb   = (const float*)d_in[15];
    const float* te_W  = (const float*)d_in[16];
    const float* te_b  = (const float*)d_in[17];
    const float* te_v  = (const float*)d_in[18];
    const float* ue1_Wq = (const float*)d_in[19];
    const float* ue1_Wk = (const float*)d_in[20];
    const float* ue1_Wv = (const float*)d_in[21];
    const float* ue2_Wq = (const float*)d_in[22];
    const float* ue2_Wk = (const float*)d_in[23];
    const float* ue2_Wv = (const float*)d_in[24];
    const float* ue3_Wq = (const float*)d_in[25];
    const float* ue3_Wk = (const float*)d_in[26];
    const float* ue3_Wv = (const float*)d_in[27];
    const float* g1_W  = (const float*)d_in[28];
    const float* g1_as = (const float*)d_in[29];
    const float* g1_ad = (const float*)d_in[30];
    const float* g2_W  = (const float*)d_in[31];
    const float* g2_as = (const float*)d_in[32];
    const float* g2_ad = (const float*)d_in[33];
    const float* cg1_Ws = (const float*)d_in[34];
    const float* cg1_Wd = (const float*)d_in[35];
    const float* cg1_as = (const float*)d_in[36];
    const float* cg1_ad = (const float*)d_in[37];
    const float* cg2_Ws = (const float*)d_in[38];
    const float* cg2_Wd = (const float*)d_in[39];
    const float* cg2_as = (const float*)d_in[40];
    const float* cg2_ad = (const float*)d_in[41];
    const float* sa_W  = (const float*)d_in[42];
    const float* sa_b  = (const float*)d_in[43];
    const float* sa_v  = (const float*)d_in[44];
    const float* gate_W = (const float*)d_in[45];
    const float* gate_b = (const float*)d_in[46];
    const float* ww_W  = (const float*)d_in[47];
    const float* ww_b  = (const float*)d_in[48];
    float* out = (float*)d_out;

    // ---- workspace carve
    char* p = (char*)d_ws;
    auto alloc = [&](size_t bytes) -> void* {
        void* r = (void*)p;
        p += (bytes + 255) & ~(size_t)255;
        return r;
    };
    int* g_off  = (int*)alloc((Nq + 1) * 4);
    int* bn_off = (int*)alloc((Nq + 1) * 4);
    int* bw_off = (int*)alloc((NEWSq + 1) * 4);
    int* g_src  = (int*)alloc(Eq * 4);
    int* bn_src = (int*)alloc(BEq * 4);
    int* bw_src = (int*)alloc(BEq * 4);
    int* cnt3   = (int*)alloc((2 * Nq + NEWSq) * 4);   // cg | cbn | cbw contiguous
    int* cur3   = (int*)alloc((2 * Nq + NEWSq) * 4);
    int* cg  = cnt3, *cbn = cnt3 + Nq, *cbw = cnt3 + 2 * Nq;
    int* curg = cur3, *curbn = cur3 + Nq, *curbw = cur3 + 2 * Nq;

    float* wscore  = (float*)alloc(WVOCq * 4);
    float* UTraw   = (float*)alloc((size_t)Bq * Hq * 128 * 4);
    float* UT3     = (float*)alloc((size_t)Bq * Hq * 128 * 4);
    float* news1   = (float*)alloc((size_t)NEWSq * 128 * 4);
    float* NC1     = (float*)alloc((size_t)NEWSq * 128 * 4);
    float* news2   = (float*)alloc((size_t)NEWSq * 128 * 4);
    float* NC2     = (float*)alloc((size_t)NEWSq * 128 * 4);
    float* newsS1  = (float*)alloc((size_t)NEWSq * 128 * 4);   // vb / hs_news
    float* v0      = (float*)alloc((size_t)Nq * 128 * 4);
    float* v1      = (float*)alloc((size_t)Nq * 128 * 4);
    float* nc1     = (float*)alloc((size_t)Nq * 128 * 4);
    float* v2      = (float*)alloc((size_t)Nq * 128 * 4);
    float* nc2     = (float*)alloc((size_t)Nq * 128 * 4);
    float* nodeS1  = (float*)alloc((size_t)Nq * 128 * 4);      // qb / hs_node
    float* nodeS2  = (float*)alloc((size_t)Nq * 128 * 4);      // kb
    float* es_node = (float*)alloc(Nq * 4);
    float* ed_node = (float*)alloc(Nq * 4);
    float* es_news = (float*)alloc(NEWSq * 4);
    float* ed_news = (float*)alloc(NEWSq * 4);
    float* gate    = (float*)alloc(Nq * 4);
    float* score_bh = (float*)alloc(Bq * Hq * 4);
    float* user_vec = (float*)alloc(Bq * 128 * 4);
    float* pooled   = (float*)alloc((size_t)Bq * 6 * 128 * 4);

    float* qb = nodeS1;   // aliases (temporally disjoint)
    float* kb = nodeS2;
    float* vb = newsS1;

    const int MH = Bq * Hq;          // 6400
    const int nbMH   = (MH + 31) / 32;      // 200
    const int nbNode = (Nq + 31) / 32;      // 320
    const int nbNews = (NEWSq + 31) / 32;   // 220
    const int nbWS   = (WVOCq + 31) / 32;   // 1563
    const int TOTE = Eq + 2 * BEq;
    const int BIG = 0x7fffffff;

    auto mkjob = [](const float* A, const float* W, float* C, const float* q0, const float* q1,
                    float* o0, float* o1, int M, int end, int amap) {
        MMJob j; j.A = A; j.W = W; j.C = C; j.q0 = q0; j.q1 = q1; j.o0 = o0; j.o1 = o1;
        j.M = M; j.blk_end = end; j.amap = amap; return j;
    };
    auto mkea = [](const int* off, const int* srcs, const float* es, const float* ed,
                   const float* Hsrc, const float* Xdst, float* Out, int nseg, int mode) {
        EASet s; s.off = off; s.srcs = srcs; s.es = es; s.ed = ed; s.Hsrc = Hsrc;
        s.Xdst = Xdst; s.Out = Out; s.nseg = nseg; s.mode = mode; return s;
    };
    EASet eaNone = mkea(nullptr, nullptr, nullptr, nullptr, nullptr, nullptr, nullptr, 0, 0);

    // ---- CSR build (3 segmentations, fused)
    hipMemsetAsync(cnt3, 0, (size_t)(2 * Nq + NEWSq) * 4, stream);
    k_count_all<<<(TOTE + 255) / 256, 256, 0, stream>>>(ei_dst, bi_node, bi_news, cg, cbn, cbw);
    k_scan3<<<3, 1024, 0, stream>>>(cg, cbn, cbw, g_off, bn_off, bw_off, curg, curbn, curbw);
    k_scatter_all<<<(TOTE + 255) / 256, 256, 0, stream>>>(ei_src, ei_dst, bi_news, bi_node,
            curg, curbn, curbw, g_src, bn_src, bw_src);

    // ---- titles: per-word score = tanh(word_emb@te_W + te_b)@te_v
    k_mm_tanh<<<nbWS, 256, 0, stream>>>(word_emb, te_W, WVOCq, te_b, te_v, wscore);
    k_title_pool<<<Bq * Sq, 128, 0, stream>>>(title_tok, wscore, word_emb,
            hist_seqs, hist_lens, pos_seq, pos_len, neg_seqs, neg_lens, UTraw, news1);
    // ---- node embeddings
    k_embed<<<(Nq * 32 + 255) / 256, 256, 0, stream>>>(nodes, ent_emb, v0, Nq);

    // ---- attn1 (user titles -> news1 user slots)
    {
        MMJobs js;
        js.j[0] = mkjob(UTraw, ue1_Wq, qb, nullptr, nullptr, nullptr, nullptr, MH, nbMH, 0);
        js.j[1] = mkjob(UTraw, ue1_Wk, kb, nullptr, nullptr, nullptr, nullptr, MH, 2 * nbMH, 0);
        js.j[2] = mkjob(UTraw, ue1_Wv, vb, nullptr, nullptr, nullptr, nullptr, MH, 3 * nbMH, 0);
        js.j[3] = mkjob(nullptr, nullptr, nullptr, nullptr, nullptr, nullptr, nullptr, 0, BIG, 0);
        k_mm_jobs<<<3 * nbMH, 256, 0, stream>>>(js);
    }
    k_self_attn<<<Bq, 256, 0, stream>>>(qb, kb, vb, news1, Sq * 128);

    // ---- GAT 1: v1 = gat(v0)
    {
        MMJobs js;
        js.j[0] = mkjob(v0, g1_W, nodeS1, g1_as, g1_ad, es_node, ed_node, Nq, nbNode, 0);
        js.j[1] = js.j[2] = js.j[3] = mkjob(nullptr, nullptr, nullptr, nullptr, nullptr, nullptr, nullptr, 0, BIG, 0);
        k_mm_jobs<<<nbNode, 256, 0, stream>>>(js);
    }
    k_edge_agg2<<<Nq, 128, 0, stream>>>(
        mkea(g_off, g_src, es_node, ed_node, nodeS1, nullptr, v1, Nq, 0), eaNone,
        nullptr, nullptr, nullptr);

    // ---- cross 1: all four matmuls fused, then both edge_aggs fused
    {
        MMJobs js;
        js.j[0] = mkjob(news1, cg1_Ws, newsS1, cg1_as, nullptr, es_news, nullptr, NEWSq, nbNews, 0);
        js.j[1] = mkjob(v1,    cg1_Wd, nullptr, cg1_ad, nullptr, ed_node, nullptr, Nq, nbNews + nbNode, 0);
        js.j[2] = mkjob(v1,    cg1_Ws, nodeS1,  cg1_as, nullptr, es_node, nullptr, Nq, nbNews + 2 * nbNode, 0);
        js.j[3] = mkjob(news1, cg1_Wd, nullptr, cg1_ad, nullptr, ed_news, nullptr, NEWSq, BIG, 0);
        k_mm_jobs<<<2 * nbNews + 2 * nbNode, 256, 0, stream>>>(js);
    }
    k_edge_agg2<<<Nq + NEWSq, 128, 0, stream>>>(
        mkea(bn_off, bn_src, es_news, ed_node, newsS1, v1, nc1, Nq, 1),
        mkea(bw_off, bw_src, es_node, ed_news, nodeS1, news1, NC1, NEWSq, 1),
        nullptr, nullptr, nullptr);

    // ---- attn2 (NC1 user slots gathered directly) + copy targets
    {
        MMJobs js;
        js.j[0] = mkjob(NC1, ue2_Wq, qb, nullptr, nullptr, nullptr, nullptr, MH, nbMH, 1);
        js.j[1] = mkjob(NC1, ue2_Wk, kb, nullptr, nullptr, nullptr, nullptr, MH, 2 * nbMH, 1);
        js.j[2] = mkjob(NC1, ue2_Wv, vb, nullptr, nullptr, nullptr, nullptr, MH, 3 * nbMH, 1);
        js.j[3] = mkjob(nullptr, nullptr, nullptr, nullptr, nullptr, nullptr, nullptr, 0, BIG, 0);
        k_mm_jobs<<<3 * nbMH, 256, 0, stream>>>(js);
    }
    k_self_attn<<<Bq, 256, 0, stream>>>(qb, kb, vb, news2, Sq * 128);
    k_copy_targets<<<(Bq * NEG1q * 32 + 255) / 256, 256, 0, stream>>>(NC1, news2);

    // ---- GAT 2: v2 = gat(nc1)
    {
        MMJobs js;
        js.j[0] = mkjob(nc1, g2_W, nodeS1, g2_as, g2_ad, es_node, ed_node, Nq, nbNode, 0);
        js.j[1] = js.j[2] = js.j[3] = mkjob(nullptr, nullptr, nullptr, nullptr, nullptr, nullptr, nullptr, 0, BIG, 0);
        k_mm_jobs<<<nbNode, 256, 0, stream>>>(js);
    }
    k_edge_agg2<<<Nq, 128, 0, stream>>>(
        mkea(g_off, g_src, es_node, ed_node, nodeS1, nullptr, v2, Nq, 0), eaNone,
        nullptr, nullptr, nullptr);

    // ---- cross 2 (+ fused gate dot on nc2 segment)
    {
        MMJobs js;
        js.j[0] = mkjob(news2, cg2_Ws, newsS1, cg2_as, nullptr, es_news, nullptr, NEWSq, nbNews, 0);
        js.j[1] = mkjob(v2,    cg2_Wd, nullptr, cg2_ad, nullptr, ed_node, nullptr, Nq, nbNews + nbNode, 0);
        js.j[2] = mkjob(v2,    cg2_Ws, nodeS1,  cg2_as, nullptr, es_node, nullptr, Nq, nbNews + 2 * nbNode, 0);
        js.j[3] = mkjob(news2, cg2_Wd, nullptr, cg2_ad, nullptr, ed_news, nullptr, NEWSq, BIG, 0);
        k_mm_jobs<<<2 * nbNews + 2 * nbNode, 256, 0, stream>>>(js);
    }
    k_edge_agg2<<<Nq + NEWSq, 128, 0, stream>>>(
        mkea(bn_off, bn_src, es_news, ed_node, newsS1, v2, nc2, Nq, 1),
        mkea(bw_off, bw_src, es_node, ed_news, nodeS1, news2, NC2, NEWSq, 1),
        gate_W, gate_b, gate);

    // ---- attn3 (NC2 user slots -> UT3)
    {
        MMJobs js;
        js.j[0] = mkjob(NC2, ue3_Wq, qb, nullptr, nullptr, nullptr, nullptr, MH, nbMH, 1);
        js.j[1] = mkjob(NC2, ue3_Wk, kb, nullptr, nullptr, nullptr, nullptr, MH, 2 * nbMH, 1);
        js.j[2] = mkjob(NC2, ue3_Wv, vb, nullptr, nullptr, nullptr, nullptr, MH, 3 * nbMH, 1);
        js.j[3] = mkjob(nullptr, nullptr, nullptr, nullptr, nullptr, nullptr, nullptr, 0, BIG, 0);
        k_mm_jobs<<<3 * nbMH, 256, 0, stream>>>(js);
    }
    k_self_attn<<<Bq, 256, 0, stream>>>(qb, kb, vb, UT3, Hq * 128);

    // ---- user_vec = attend_pool(UT3, sa)
    k_mm_tanh<<<nbMH, 256, 0, stream>>>(UT3, sa_W, MH, sa_b, sa_v, score_bh);
    k_user_pool<<<Bq, 128, 0, stream>>>(UT3, score_bh, user_vec);

    // ---- mask pool on nc2 (gate computed by fused edge_agg)
    k_mask_pool<<<Bq * 6, 128, 0, stream>>>(nc2, gate, hist_mask, pos_mask, neg_masks, pooled);

    // ---- final gated scores
    k_final<<<Bq * NEG1q, 128, 0, stream>>>(pooled, user_vec, NC2, ww_W, ww_b, out);
}